// Round 3
// baseline (585.065 us; speedup 1.0000x reference)
//
#include <hip/hip_runtime.h>
#include <hip/hip_bf16.h>

typedef __hip_bfloat16 bf16;

#define NEG_SLOPE 0.15f

__device__ __forceinline__ float us2f(unsigned short u) {
    unsigned int x = ((unsigned int)u) << 16;
    float f;
    __builtin_memcpy(&f, &x, 4);
    return f;
}
__device__ __forceinline__ float to_f(float v) { return v; }
__device__ __forceinline__ float to_f(bf16 v) { return __bfloat162float(v); }
__device__ __forceinline__ void st_val(float* p, size_t o, float v) { p[o] = v; }
__device__ __forceinline__ void st_val(bf16* p, size_t o, float v) { p[o] = __float2bfloat16(v); }

__device__ __forceinline__ void ld4(const float* A, size_t o, float v[4]) {
    float4 t = *(const float4*)(A + o);
    v[0] = t.x; v[1] = t.y; v[2] = t.z; v[3] = t.w;
}
__device__ __forceinline__ void ld4(const bf16* A, size_t o, float v[4]) {
    union { uint2 u; unsigned short s[4]; } t;
    t.u = *(const uint2*)((const unsigned short*)A + o);
#pragma unroll
    for (int i = 0; i < 4; ++i) v[i] = us2f(t.s[i]);
}

// ------------------------------------------------------------ dtype detection
// Writes flag[0]=1 if x is packed bf16, 0 if fp32. Looks at low 16 bits of the
// first 1024 words: genuine bf16 of ~N(0,1) has exponent field in [100,140]
// (or is zero) essentially always; random fp32 mantissa bits land there ~16%.
__global__ void detect_dtype_kernel(const unsigned int* __restrict__ xw,
                                    int* __restrict__ flag) {
    __shared__ int cnt;
    int tid = threadIdx.x;
    if (tid == 0) cnt = 0;
    __syncthreads();
    int inr = 0;
    for (int k = 0; k < 4; ++k) {
        unsigned int w = xw[tid + k * 256];
        unsigned int e = (w >> 7) & 0xFF;
        if ((w & 0xFFFF) == 0 || (e >= 100 && e <= 140)) inr++;
    }
    atomicAdd(&cnt, inr);
    __syncthreads();
    if (tid == 0) flag[0] = (cnt >= 700) ? 1 : 0;
}

__global__ void convert_x_kernel(const void* __restrict__ in, float* __restrict__ out,
                                 int n, const int* __restrict__ flag) {
    int i = blockIdx.x * blockDim.x + threadIdx.x;
    if (i >= n) return;
    out[i] = (*flag) ? us2f(((const unsigned short*)in)[i]) : ((const float*)in)[i];
}

struct WtDesc {
    const void* src[12];
    float* dst[12];
    int n[12];
};

__global__ void convert_many_kernel(WtDesc d, const int* __restrict__ flag) {
    int t = blockIdx.y;
    int i = blockIdx.x * blockDim.x + threadIdx.x;
    if (i >= d.n[t]) return;
    float v = (*flag) ? us2f(((const unsigned short*)d.src[t])[i])
                      : ((const float*)d.src[t])[i];
    d.dst[t][i] = v;
}

// ---------------------------------------------------------------- CSR build
__global__ void zero_int_kernel(int* __restrict__ p, int n) {
    int i = blockIdx.x * blockDim.x + threadIdx.x;
    if (i < n) p[i] = 0;
}

__global__ void init_deg_kernel(int* __restrict__ deg, int N) {
    int i = blockIdx.x * blockDim.x + threadIdx.x;
    if (i < N) deg[i] = 1;  // self-loop
}

__global__ void count_deg_kernel(const int* __restrict__ dst, int* __restrict__ deg,
                                 int E, int N) {
    int i = blockIdx.x * blockDim.x + threadIdx.x;
    if (i < E) {
        int d = dst[i];
        d = d < 0 ? 0 : (d >= N ? N - 1 : d);
        atomicAdd(&deg[d], 1);
    }
}

__global__ void scan_kernel(const int* __restrict__ deg, int* __restrict__ offsets,
                            int* __restrict__ cursor, float* __restrict__ dis, int N) {
    __shared__ int sh[1024];
    int tid = threadIdx.x;
    int chunk = (N + 1023) >> 10;
    int s = tid * chunk;
    int e = s + chunk; if (e > N) e = N;
    int sum = 0;
    for (int i = s; i < e; ++i) sum += deg[i];
    sh[tid] = sum;
    __syncthreads();
    for (int off = 1; off < 1024; off <<= 1) {
        int v = (tid >= off) ? sh[tid - off] : 0;
        __syncthreads();
        sh[tid] += v;
        __syncthreads();
    }
    int pre = (tid > 0) ? sh[tid - 1] : 0;
    for (int i = s; i < e; ++i) {
        offsets[i] = pre;
        cursor[i] = pre;
        int d = deg[i];
        dis[i] = rsqrtf((float)(d < 1 ? 1 : d));
        pre += d;
    }
    if (tid == 0) offsets[N] = sh[1023];
}

__global__ void fill_csr_kernel(const int* __restrict__ src, const int* __restrict__ dst,
                                int* __restrict__ cursor, int* __restrict__ csr_src,
                                int E, int N, int Etot) {
    int i = blockIdx.x * blockDim.x + threadIdx.x;
    int s, d;
    if (i < E) { s = src[i]; d = dst[i]; }
    else if (i < Etot) { s = d = i - E; }
    else return;
    s = s < 0 ? 0 : (s >= N ? N - 1 : s);
    d = d < 0 ? 0 : (d >= N ? N - 1 : d);
    int pos = atomicAdd(&cursor[d], 1);
    if (pos >= 0 && pos < Etot) csr_src[pos] = s;
}

// ---------------------------------------------------------------- aggregation
// Hout[n][f] = dis[n] * sum_e dis[src_e] * Hin[src_e][f]   (+bias, lrelu optional)
template <typename TIn, typename TOut>
__global__ void agg_kernel(const TIn* __restrict__ Hin, TOut* __restrict__ Hout,
                           const int* __restrict__ offsets, const int* __restrict__ csr_src,
                           const float* __restrict__ dis, int F, int N, int Etot,
                           const float* __restrict__ bias, int do_lrelu) {
    int node = blockIdx.x;
    int f = threadIdx.x;
    int beg = offsets[node], end = offsets[node + 1];
    beg = beg < 0 ? 0 : (beg > Etot ? Etot : beg);
    end = end < beg ? beg : (end > Etot ? Etot : end);
    float acc = 0.f;
    for (int e = beg; e < end; ++e) {
        int s = csr_src[e];
        s = s < 0 ? 0 : (s >= N ? N - 1 : s);
        acc += dis[s] * to_f(Hin[(size_t)s * F + f]);
    }
    acc *= dis[node];
    if (bias) acc += bias[f];
    if (do_lrelu) acc = (acc > 0.f) ? acc : acc * NEG_SLOPE;
    st_val(Hout, (size_t)node * F + f, acc);
}

// ---------------------------------------------------------------- GEMM
// C[M x Nn] = A[M x K] * B[K x Nn](fp32)  (+bias, lrelu optional); f32 accumulate
template <typename TA, typename TC>
__global__ __launch_bounds__(256) void gemm_kernel(
    const TA* __restrict__ A, const float* __restrict__ B, TC* __restrict__ C,
    int M, int K, int Nn, const float* __restrict__ bias, int do_lrelu) {
    const int BM = 128, BN = 128, BK = 16;
    __shared__ float As[BK][BM + 4];
    __shared__ float Bs[BK][BN + 4];
    int tid = threadIdx.x;
    int row0 = blockIdx.y * BM;
    int col0 = blockIdx.x * BN;
    int tx = tid & 15;
    int ty = tid >> 4;
    float acc[8][8];
#pragma unroll
    for (int i = 0; i < 8; ++i)
#pragma unroll
        for (int j = 0; j < 8; ++j) acc[i][j] = 0.f;

    int ar = tid >> 2;          // 0..63
    int ac = (tid & 3) << 2;    // 0,4,8,12
    int kb = tid >> 4;          // 0..15
    int cb = (tid & 15) << 3;   // 0..120

    for (int k0 = 0; k0 < K; k0 += BK) {
#pragma unroll
        for (int h = 0; h < 2; ++h) {
            int gr = row0 + ar + h * 64;
            float v[4] = {0.f, 0.f, 0.f, 0.f};
            if (gr < M) ld4(A, (size_t)gr * K + k0 + ac, v);
            As[ac + 0][ar + h * 64] = v[0];
            As[ac + 1][ar + h * 64] = v[1];
            As[ac + 2][ar + h * 64] = v[2];
            As[ac + 3][ar + h * 64] = v[3];
        }
        {
            const float* bp2 = B + (size_t)(k0 + kb) * Nn + col0 + cb;
            float4 v0 = *(const float4*)bp2;
            float4 v1 = *(const float4*)(bp2 + 4);
            Bs[kb][cb + 0] = v0.x; Bs[kb][cb + 1] = v0.y;
            Bs[kb][cb + 2] = v0.z; Bs[kb][cb + 3] = v0.w;
            Bs[kb][cb + 4] = v1.x; Bs[kb][cb + 5] = v1.y;
            Bs[kb][cb + 6] = v1.z; Bs[kb][cb + 7] = v1.w;
        }
        __syncthreads();
#pragma unroll
        for (int kk = 0; kk < BK; ++kk) {
            float a[8], b[8];
            *(float4*)&a[0] = *(const float4*)&As[kk][ty * 8];
            *(float4*)&a[4] = *(const float4*)&As[kk][ty * 8 + 4];
            *(float4*)&b[0] = *(const float4*)&Bs[kk][tx * 8];
            *(float4*)&b[4] = *(const float4*)&Bs[kk][tx * 8 + 4];
#pragma unroll
            for (int i = 0; i < 8; ++i)
#pragma unroll
                for (int j = 0; j < 8; ++j) acc[i][j] += a[i] * b[j];
        }
        __syncthreads();
    }
#pragma unroll
    for (int i = 0; i < 8; ++i) {
        int gr = row0 + ty * 8 + i;
        if (gr >= M) continue;
#pragma unroll
        for (int j = 0; j < 8; ++j) {
            int gc = col0 + tx * 8 + j;
            float v = acc[i][j];
            if (bias) v += bias[gc];
            if (do_lrelu) v = (v > 0.f) ? v : v * NEG_SLOPE;
            st_val(C, (size_t)gr * Nn + gc, v);
        }
    }
}

// ---------------------------------------------------------------- fused head
template <typename T>
__global__ void head_kernel(const T* __restrict__ H,
                            const float* __restrict__ Wp, const float* __restrict__ bp,
                            const float* __restrict__ Wf1, const float* __restrict__ bf1v,
                            const float* __restrict__ Wf2, const float* __restrict__ bf2v,
                            void* __restrict__ out, int N, const int* __restrict__ flag) {
    int n = blockIdx.x * blockDim.x + threadIdx.x;
    if (n >= N) return;
    const T* h = H + (size_t)n * 128;
    float h4[16];
#pragma unroll
    for (int j = 0; j < 16; ++j) h4[j] = bp[j];
    for (int k = 0; k < 128; ++k) {
        float hv = to_f(h[k]);
#pragma unroll
        for (int j = 0; j < 16; ++j) h4[j] += hv * Wp[k * 16 + j];
    }
    float h5[32];
#pragma unroll
    for (int j = 0; j < 32; ++j) h5[j] = bf1v[j];
#pragma unroll
    for (int k = 0; k < 16; ++k) {
#pragma unroll
        for (int j = 0; j < 32; ++j) h5[j] += h4[k] * Wf1[k * 32 + j];
    }
#pragma unroll
    for (int j = 0; j < 32; ++j) h5[j] = (h5[j] > 0.f) ? h5[j] : h5[j] * NEG_SLOPE;
    float o[2];
#pragma unroll
    for (int j = 0; j < 2; ++j) {
        float a = bf2v[j];
#pragma unroll
        for (int k = 0; k < 32; ++k) a += h5[k] * Wf2[k * 2 + j];
        o[j] = a;
    }
    if (*flag) {
        bf16* ob = (bf16*)out;
        ob[(size_t)n * 2 + 0] = __float2bfloat16(o[0]);
        ob[(size_t)n * 2 + 1] = __float2bfloat16(o[1]);
    } else {
        float* of = (float*)out;
        of[(size_t)n * 2 + 0] = o[0];
        of[(size_t)n * 2 + 1] = o[1];
    }
}

// ---------------------------------------------------------------- launch
extern "C" void kernel_launch(void* const* d_in, const int* in_sizes, int n_in,
                              void* d_out, int out_size, void* d_ws, size_t ws_size,
                              hipStream_t stream) {
    const int* ei = (const int*)d_in[1];

    const int N = in_sizes[0] / 128;   // 20000
    const int E = in_sizes[1] / 2;     // 320000
    const int Etot = E + N;
    const int* src = ei;
    const int* dst = ei + E;

    uintptr_t p = (uintptr_t)d_ws;
    auto alloc = [&](size_t bytes) -> void* {
        p = (p + 255) & ~(uintptr_t)255;
        void* r = (void*)p;
        p += bytes;
        return r;
    };
    int*   flag    = (int*)alloc(4);
    float* xf      = (float*)alloc((size_t)N * 128 * 4);
    int*   deg     = (int*)alloc((size_t)N * 4);
    int*   offsets = (int*)alloc((size_t)(N + 1) * 4);
    int*   cursor  = (int*)alloc((size_t)N * 4);
    float* dis     = (float*)alloc((size_t)N * 4);
    int*   csr_src = (int*)alloc((size_t)Etot * 4);

    // converted weights (fp32)
    WtDesc wd;
    // order: W1,b1,W2,b2,W3,b3,Wp,bp,Wf1,bf1,Wf2,bf2  <- d_in[3..14]
    int maxn = 0;
    for (int t = 0; t < 12; ++t) {
        int n = in_sizes[3 + t];
        wd.src[t] = d_in[3 + t];
        wd.n[t] = n;
        wd.dst[t] = (float*)alloc((size_t)n * 4);
        if (n > maxn) maxn = n;
    }
    const float *W1 = wd.dst[0], *b1 = wd.dst[1], *W2 = wd.dst[2], *b2 = wd.dst[3];
    const float *W3 = wd.dst[4], *b3 = wd.dst[5], *Wp = wd.dst[6], *bp = wd.dst[7];
    const float *Wf1 = wd.dst[8], *bf1v = wd.dst[9], *Wf2 = wd.dst[10], *bf2v = wd.dst[11];

    size_t base_used = p - (uintptr_t)d_ws;
    size_t f32_need = base_used + 512 + (size_t)N * 512 * 4 + (size_t)N * 256 * 4;
    bool use_f32 = (ws_size >= f32_need);

    // ---- dtype detect + convert ----
    detect_dtype_kernel<<<1, 256, 0, stream>>>((const unsigned int*)d_in[0], flag);
    convert_x_kernel<<<(N * 128 + 255) / 256, 256, 0, stream>>>(d_in[0], xf, N * 128, flag);
    {
        dim3 g((maxn + 255) / 256, 12);
        convert_many_kernel<<<g, 256, 0, stream>>>(wd, flag);
    }

    // ---- CSR build ----
    zero_int_kernel<<<(Etot + 255) / 256, 256, 0, stream>>>(csr_src, Etot);
    init_deg_kernel<<<(N + 255) / 256, 256, 0, stream>>>(deg, N);
    count_deg_kernel<<<(E + 255) / 256, 256, 0, stream>>>(dst, deg, E, N);
    scan_kernel<<<1, 1024, 0, stream>>>(deg, offsets, cursor, dis, N);
    fill_csr_kernel<<<(Etot + 255) / 256, 256, 0, stream>>>(src, dst, cursor, csr_src,
                                                            E, N, Etot);

    if (use_f32) {
        float* bufA = (float*)alloc((size_t)N * 512 * 4);  // H1 / H2 / H3
        float* bufB = (float*)alloc((size_t)N * 256 * 4);  // t0 / t2 / t3

        agg_kernel<float, float><<<N, 128, 0, stream>>>(xf, bufB, offsets, csr_src, dis,
                                                        128, N, Etot, nullptr, 0);
        {
            dim3 g(4, (N + 127) / 128);
            gemm_kernel<float, float><<<g, 256, 0, stream>>>(bufB, W1, bufA, N, 128, 512, b1, 1);
        }
        {
            dim3 g(2, (N + 127) / 128);
            gemm_kernel<float, float><<<g, 256, 0, stream>>>(bufA, W2, bufB, N, 512, 256, nullptr, 0);
        }
        agg_kernel<float, float><<<N, 256, 0, stream>>>(bufB, bufA, offsets, csr_src, dis,
                                                        256, N, Etot, b2, 1);
        {
            dim3 g(1, (N + 127) / 128);
            gemm_kernel<float, float><<<g, 256, 0, stream>>>(bufA, W3, bufB, N, 256, 128, nullptr, 0);
        }
        agg_kernel<float, float><<<N, 128, 0, stream>>>(bufB, bufA, offsets, csr_src, dis,
                                                        128, N, Etot, b3, 1);
        head_kernel<float><<<(N + 255) / 256, 256, 0, stream>>>(bufA, Wp, bp, Wf1, bf1v,
                                                                Wf2, bf2v, d_out, N, flag);
    } else {
        // bf16-intermediate fallback: fp32 accumulate, bf16 storage of intermediates
        bf16* bufA = (bf16*)alloc((size_t)N * 512 * 2);
        bf16* bufB = (bf16*)alloc((size_t)N * 256 * 2);

        agg_kernel<float, bf16><<<N, 128, 0, stream>>>(xf, bufB, offsets, csr_src, dis,
                                                       128, N, Etot, nullptr, 0);
        {
            dim3 g(4, (N + 127) / 128);
            gemm_kernel<bf16, bf16><<<g, 256, 0, stream>>>(bufB, W1, bufA, N, 128, 512, b1, 1);
        }
        {
            dim3 g(2, (N + 127) / 128);
            gemm_kernel<bf16, bf16><<<g, 256, 0, stream>>>(bufA, W2, bufB, N, 512, 256, nullptr, 0);
        }
        agg_kernel<bf16, bf16><<<N, 256, 0, stream>>>(bufB, bufA, offsets, csr_src, dis,
                                                      256, N, Etot, b2, 1);
        {
            dim3 g(1, (N + 127) / 128);
            gemm_kernel<bf16, bf16><<<g, 256, 0, stream>>>(bufA, W3, bufB, N, 256, 128, nullptr, 0);
        }
        agg_kernel<bf16, bf16><<<N, 128, 0, stream>>>(bufB, bufA, offsets, csr_src, dis,
                                                      128, N, Etot, b3, 1);
        head_kernel<bf16><<<(N + 255) / 256, 256, 0, stream>>>(bufA, Wp, bp, Wf1, bf1v,
                                                               Wf2, bf2v, d_out, N, flag);
    }
}

// Round 4
// 444.122 us; speedup vs baseline: 1.3174x; 1.3174x over previous
//
#include <hip/hip_runtime.h>
#include <hip/hip_bf16.h>

typedef __hip_bfloat16 bf16;
typedef unsigned short ushort_t;
typedef __attribute__((ext_vector_type(8))) short short8v;
typedef __attribute__((ext_vector_type(4))) float floatx4;

#define NEG_SLOPE 0.15f

__device__ __forceinline__ float us2f(unsigned short u) {
    unsigned int x = ((unsigned int)u) << 16;
    float f;
    __builtin_memcpy(&f, &x, 4);
    return f;
}
__device__ __forceinline__ unsigned short f2us(float v) {
    bf16 h = __float2bfloat16(v);
    unsigned short u;
    __builtin_memcpy(&u, &h, 2);
    return u;
}
__device__ __forceinline__ void split2(float v, unsigned short& hi, unsigned short& lo) {
    hi = f2us(v);
    lo = f2us(v - us2f(hi));
}

// ------------------------------------------------------------ dtype detection
__global__ void detect_dtype_kernel(const unsigned int* __restrict__ xw,
                                    int* __restrict__ flag) {
    __shared__ int cnt;
    int tid = threadIdx.x;
    if (tid == 0) cnt = 0;
    __syncthreads();
    int inr = 0;
    for (int k = 0; k < 4; ++k) {
        unsigned int w = xw[tid + k * 256];
        unsigned int e = (w >> 7) & 0xFF;
        if ((w & 0xFFFF) == 0 || (e >= 100 && e <= 140)) inr++;
    }
    atomicAdd(&cnt, inr);
    __syncthreads();
    if (tid == 0) flag[0] = (cnt >= 700) ? 1 : 0;
}

__global__ void convert_x_kernel(const void* __restrict__ in, float* __restrict__ out,
                                 int n, const int* __restrict__ flag) {
    int i = blockIdx.x * blockDim.x + threadIdx.x;
    if (i >= n) return;
    out[i] = (*flag) ? us2f(((const unsigned short*)in)[i]) : ((const float*)in)[i];
}

struct WtDesc {
    const void* src[9];
    float* dst[9];
    int n[9];
};

__global__ void convert_many_kernel(WtDesc d, const int* __restrict__ flag) {
    int t = blockIdx.y;
    int i = blockIdx.x * blockDim.x + threadIdx.x;
    if (i >= d.n[t]) return;
    float v = (*flag) ? us2f(((const unsigned short*)d.src[t])[i])
                      : ((const float*)d.src[t])[i];
    d.dst[t][i] = v;
}

// Transpose+split W[K x Nn] -> Wt_hi/Wt_lo [Nn x K] bf16 bits
struct WSplit {
    const void* src[3];
    ushort_t* hi[3];
    ushort_t* lo[3];
    int K[3], Nn[3];
};

__global__ void wsplit_kernel(WSplit d, const int* __restrict__ flag) {
    int t = blockIdx.y;
    int i = blockIdx.x * blockDim.x + threadIdx.x;
    int K = d.K[t], Nn = d.Nn[t];
    if (i >= K * Nn) return;
    int n = i / K, k = i - n * K;
    float v = (*flag) ? us2f(((const unsigned short*)d.src[t])[(size_t)k * Nn + n])
                      : ((const float*)d.src[t])[(size_t)k * Nn + n];
    unsigned short hi, lo;
    split2(v, hi, lo);
    d.hi[t][i] = hi;
    d.lo[t][i] = lo;
}

// ---------------------------------------------------------------- CSR build
__global__ void init_deg_kernel(int* __restrict__ deg, int N) {
    int i = blockIdx.x * blockDim.x + threadIdx.x;
    if (i < N) deg[i] = 1;  // self-loop
}

__global__ void count_deg_kernel(const int* __restrict__ dst, int* __restrict__ deg,
                                 int E, int N) {
    int i = blockIdx.x * blockDim.x + threadIdx.x;
    if (i < E) {
        int d = dst[i];
        d = d < 0 ? 0 : (d >= N ? N - 1 : d);
        atomicAdd(&deg[d], 1);
    }
}

__global__ void scan_kernel(const int* __restrict__ deg, int* __restrict__ offsets,
                            int* __restrict__ cursor, float* __restrict__ dis, int N) {
    __shared__ int sh[1024];
    int tid = threadIdx.x;
    int chunk = (N + 1023) >> 10;
    int s = tid * chunk;
    int e = s + chunk; if (e > N) e = N;
    int sum = 0;
    for (int i = s; i < e; ++i) sum += deg[i];
    sh[tid] = sum;
    __syncthreads();
    for (int off = 1; off < 1024; off <<= 1) {
        int v = (tid >= off) ? sh[tid - off] : 0;
        __syncthreads();
        sh[tid] += v;
        __syncthreads();
    }
    int pre = (tid > 0) ? sh[tid - 1] : 0;
    for (int i = s; i < e; ++i) {
        offsets[i] = pre;
        cursor[i] = pre;
        int d = deg[i];
        dis[i] = rsqrtf((float)(d < 1 ? 1 : d));
        pre += d;
    }
    if (tid == 0) offsets[N] = sh[1023];
}

__global__ void fill_csr_kernel(const int* __restrict__ src, const int* __restrict__ dst,
                                int* __restrict__ cursor, int* __restrict__ csr_src,
                                int E, int N, int Etot) {
    int i = blockIdx.x * blockDim.x + threadIdx.x;
    int s, d;
    if (i < E) { s = src[i]; d = dst[i]; }
    else if (i < Etot) { s = d = i - E; }
    else return;
    s = s < 0 ? 0 : (s >= N ? N - 1 : s);
    d = d < 0 ? 0 : (d >= N ? N - 1 : d);
    int pos = atomicAdd(&cursor[d], 1);
    if (pos >= 0 && pos < Etot) csr_src[pos] = s;
}

// ---------------------------------------------------------------- aggregation
// OUT_MODE: 0 = fp32 out, 1 = split bf16 out
template <int OUT_MODE>
__global__ void agg_kernel(const float* __restrict__ Hin, float* __restrict__ OutF,
                           ushort_t* __restrict__ Ohi, ushort_t* __restrict__ Olo,
                           const int* __restrict__ offsets, const int* __restrict__ csr_src,
                           const float* __restrict__ dis, int F, int N, int Etot,
                           const float* __restrict__ bias, int do_lrelu) {
    int node = blockIdx.x;
    int f = threadIdx.x;
    int beg = offsets[node], end = offsets[node + 1];
    beg = beg < 0 ? 0 : (beg > Etot ? Etot : beg);
    end = end < beg ? beg : (end > Etot ? Etot : end);
    float acc = 0.f;
    for (int e = beg; e < end; ++e) {
        int s = csr_src[e];
        s = s < 0 ? 0 : (s >= N ? N - 1 : s);
        acc += dis[s] * Hin[(size_t)s * F + f];
    }
    acc *= dis[node];
    if (bias) acc += bias[f];
    if (do_lrelu) acc = (acc > 0.f) ? acc : acc * NEG_SLOPE;
    size_t idx = (size_t)node * F + f;
    if (OUT_MODE == 0) {
        OutF[idx] = acc;
    } else {
        unsigned short hi, lo;
        split2(acc, hi, lo);
        Ohi[idx] = hi;
        Olo[idx] = lo;
    }
}

// ---------------------------------------------------------------- MFMA GEMM
// C[M x Nn] = (Ahi+Alo)[M x K] * (Bhi+Blo)  with B given TRANSPOSED: Bt[Nn x K]
// Tile: 128x64, 256 threads = 4 waves (2x2), each wave 64x32 (4x2 MFMA 16x16x32 tiles).
// 3 MFMA per tile pair: hi*hi + hi*lo + lo*hi (fp32-equivalent accuracy).
// OUT_SPLIT: 0 = fp32 C, 1 = split bf16 (Chi/Clo)
template <int OUT_SPLIT>
__global__ __launch_bounds__(256) void mfma_gemm_kernel(
    const ushort_t* __restrict__ Ahi, const ushort_t* __restrict__ Alo,
    const ushort_t* __restrict__ Bthi, const ushort_t* __restrict__ Btlo,
    float* __restrict__ Cf, ushort_t* __restrict__ Chi, ushort_t* __restrict__ Clo,
    int M, int K, int Nn, const float* __restrict__ bias, int do_lrelu) {
    __shared__ ushort_t Ah[128 * 40];
    __shared__ ushort_t Al[128 * 40];
    __shared__ ushort_t Bh[64 * 40];
    __shared__ ushort_t Bl[64 * 40];

    int tid = threadIdx.x;
    int row0 = blockIdx.y * 128;
    int col0 = blockIdx.x * 64;
    int lane = tid & 63;
    int w = tid >> 6;
    int quad = lane >> 4;
    int col = lane & 15;
    int wr = (w >> 1) * 64;   // wave row offset in tile
    int wc = (w & 1) * 32;    // wave col offset in tile

    floatx4 acc[4][2];
#pragma unroll
    for (int i = 0; i < 4; ++i)
#pragma unroll
        for (int j = 0; j < 2; ++j) acc[i][j] = (floatx4){0.f, 0.f, 0.f, 0.f};

    int arow = tid >> 1;           // 0..127
    int aseg = (tid & 1) * 16;     // 0 or 16 (bf16 elems)
    int bcol = tid >> 2;           // 0..63
    int bseg = (tid & 3) * 8;      // 0,8,16,24

    for (int k0 = 0; k0 < K; k0 += 32) {
        // stage A (hi+lo): each thread 16 bf16 from one row
        {
            uint4 h0 = {0, 0, 0, 0}, h1 = {0, 0, 0, 0};
            uint4 l0 = {0, 0, 0, 0}, l1 = {0, 0, 0, 0};
            if (row0 + arow < M) {
                size_t g = (size_t)(row0 + arow) * K + k0 + aseg;
                h0 = *(const uint4*)(Ahi + g);
                h1 = *(const uint4*)(Ahi + g + 8);
                l0 = *(const uint4*)(Alo + g);
                l1 = *(const uint4*)(Alo + g + 8);
            }
            int lb = arow * 40 + aseg;
            *(uint4*)&Ah[lb] = h0;
            *(uint4*)&Ah[lb + 8] = h1;
            *(uint4*)&Al[lb] = l0;
            *(uint4*)&Al[lb + 8] = l1;
        }
        // stage Bt (hi+lo): each thread 8 bf16 from one col-row of Bt
        {
            size_t g = (size_t)(col0 + bcol) * K + k0 + bseg;
            int lb = bcol * 40 + bseg;
            *(uint4*)&Bh[lb] = *(const uint4*)(Bthi + g);
            *(uint4*)&Bl[lb] = *(const uint4*)(Btlo + g);
        }
        __syncthreads();

        short8v af_h[4], af_l[4], bf_h[2], bf_l[2];
#pragma unroll
        for (int rt = 0; rt < 4; ++rt) {
            int r = (wr + rt * 16 + col) * 40 + quad * 8;
            af_h[rt] = *(const short8v*)&Ah[r];
            af_l[rt] = *(const short8v*)&Al[r];
        }
#pragma unroll
        for (int ct = 0; ct < 2; ++ct) {
            int c = (wc + ct * 16 + col) * 40 + quad * 8;
            bf_h[ct] = *(const short8v*)&Bh[c];
            bf_l[ct] = *(const short8v*)&Bl[c];
        }
#pragma unroll
        for (int rt = 0; rt < 4; ++rt)
#pragma unroll
            for (int ct = 0; ct < 2; ++ct) {
                acc[rt][ct] = __builtin_amdgcn_mfma_f32_16x16x32_bf16(
                    af_h[rt], bf_h[ct], acc[rt][ct], 0, 0, 0);
                acc[rt][ct] = __builtin_amdgcn_mfma_f32_16x16x32_bf16(
                    af_h[rt], bf_l[ct], acc[rt][ct], 0, 0, 0);
                acc[rt][ct] = __builtin_amdgcn_mfma_f32_16x16x32_bf16(
                    af_l[rt], bf_h[ct], acc[rt][ct], 0, 0, 0);
            }
        __syncthreads();
    }

    // epilogue: C/D layout col=lane&15, row=quad*4+reg
#pragma unroll
    for (int rt = 0; rt < 4; ++rt) {
#pragma unroll
        for (int ct = 0; ct < 2; ++ct) {
            int gcol = col0 + wc + ct * 16 + col;
            float bv = bias ? bias[gcol] : 0.f;
#pragma unroll
            for (int r = 0; r < 4; ++r) {
                int grow = row0 + wr + rt * 16 + quad * 4 + r;
                if (grow >= M) continue;
                float v = acc[rt][ct][r] + bv;
                if (do_lrelu) v = (v > 0.f) ? v : v * NEG_SLOPE;
                size_t idx = (size_t)grow * Nn + gcol;
                if (OUT_SPLIT == 0) {
                    Cf[idx] = v;
                } else {
                    unsigned short hi, lo;
                    split2(v, hi, lo);
                    Chi[idx] = hi;
                    Clo[idx] = lo;
                }
            }
        }
    }
}

// ---------------------------------------------------------------- fused head
__global__ void head_kernel(const float* __restrict__ H,
                            const float* __restrict__ Wp, const float* __restrict__ bp,
                            const float* __restrict__ Wf1, const float* __restrict__ bf1v,
                            const float* __restrict__ Wf2, const float* __restrict__ bf2v,
                            void* __restrict__ out, int N, const int* __restrict__ flag) {
    int n = blockIdx.x * blockDim.x + threadIdx.x;
    if (n >= N) return;
    const float* h = H + (size_t)n * 128;
    float h4[16];
#pragma unroll
    for (int j = 0; j < 16; ++j) h4[j] = bp[j];
    for (int k = 0; k < 128; ++k) {
        float hv = h[k];
#pragma unroll
        for (int j = 0; j < 16; ++j) h4[j] += hv * Wp[k * 16 + j];
    }
    float h5[32];
#pragma unroll
    for (int j = 0; j < 32; ++j) h5[j] = bf1v[j];
#pragma unroll
    for (int k = 0; k < 16; ++k) {
#pragma unroll
        for (int j = 0; j < 32; ++j) h5[j] += h4[k] * Wf1[k * 32 + j];
    }
#pragma unroll
    for (int j = 0; j < 32; ++j) h5[j] = (h5[j] > 0.f) ? h5[j] : h5[j] * NEG_SLOPE;
    float o[2];
#pragma unroll
    for (int j = 0; j < 2; ++j) {
        float a = bf2v[j];
#pragma unroll
        for (int k = 0; k < 32; ++k) a += h5[k] * Wf2[k * 2 + j];
        o[j] = a;
    }
    if (*flag) {
        ushort_t* ob = (ushort_t*)out;
        ob[(size_t)n * 2 + 0] = f2us(o[0]);
        ob[(size_t)n * 2 + 1] = f2us(o[1]);
    } else {
        float* of = (float*)out;
        of[(size_t)n * 2 + 0] = o[0];
        of[(size_t)n * 2 + 1] = o[1];
    }
}

// ---------------------------------------------------------------- launch
extern "C" void kernel_launch(void* const* d_in, const int* in_sizes, int n_in,
                              void* d_out, int out_size, void* d_ws, size_t ws_size,
                              hipStream_t stream) {
    const int* ei = (const int*)d_in[1];

    const int N = in_sizes[0] / 128;   // 20000
    const int E = in_sizes[1] / 2;     // 320000
    const int Etot = E + N;
    const int* srcv = ei;
    const int* dstv = ei + E;

    uintptr_t p = (uintptr_t)d_ws;
    auto alloc = [&](size_t bytes) -> void* {
        p = (p + 255) & ~(uintptr_t)255;
        void* r = (void*)p;
        p += bytes;
        return r;
    };
    int*   flag    = (int*)alloc(4);
    int*   deg     = (int*)alloc((size_t)N * 4);
    int*   offsets = (int*)alloc((size_t)(N + 1) * 4);
    int*   cursor  = (int*)alloc((size_t)N * 4);
    float* dis     = (float*)alloc((size_t)N * 4);
    int*   csr_src = (int*)alloc((size_t)Etot * 4);

    // split/transposed GEMM weights: Wt[Nn x K] hi/lo
    const int K1 = 128, N1 = 512, K2 = 512, N2 = 256, K3 = 256, N3 = 128;
    ushort_t* W1thi = (ushort_t*)alloc((size_t)K1 * N1 * 2);
    ushort_t* W1tlo = (ushort_t*)alloc((size_t)K1 * N1 * 2);
    ushort_t* W2thi = (ushort_t*)alloc((size_t)K2 * N2 * 2);
    ushort_t* W2tlo = (ushort_t*)alloc((size_t)K2 * N2 * 2);
    ushort_t* W3thi = (ushort_t*)alloc((size_t)K3 * N3 * 2);
    ushort_t* W3tlo = (ushort_t*)alloc((size_t)K3 * N3 * 2);

    // fp32 small tensors: b1,b2,b3, Wp,bp, Wf1,bf1, Wf2,bf2
    WtDesc wd;
    const int wmap[9] = {4, 6, 8, 9, 10, 11, 12, 13, 14};  // d_in indices
    int maxn = 0;
    for (int t = 0; t < 9; ++t) {
        int n = in_sizes[wmap[t]];
        wd.src[t] = d_in[wmap[t]];
        wd.n[t] = n;
        wd.dst[t] = (float*)alloc((size_t)n * 4);
        if (n > maxn) maxn = n;
    }
    const float *b1 = wd.dst[0], *b2 = wd.dst[1], *b3 = wd.dst[2];
    const float *Wp = wd.dst[3], *bp = wd.dst[4];
    const float *Wf1 = wd.dst[5], *bf1v = wd.dst[6];
    const float *Wf2 = wd.dst[7], *bf2v = wd.dst[8];

    // big aliased region: 61.44 MB for N=20000
    char* big = (char*)alloc((size_t)N * 128 * 8 + (size_t)N * 512 * 4);
    float*    xf   = (float*)(big);                                        // [N,128] f32
    ushort_t* T0hi = (ushort_t*)(big + (size_t)N * 128 * 4);               // [N,128]
    ushort_t* T0lo = (ushort_t*)(big + (size_t)N * 128 * 6);
    ushort_t* H1hi = (ushort_t*)(big + (size_t)N * 128 * 8);               // [N,512]
    ushort_t* H1lo = (ushort_t*)(big + (size_t)N * 128 * 8 + (size_t)N * 512 * 2);
    float*    t2   = (float*)(big);                                        // [N,256] f32
    ushort_t* H2hi = (ushort_t*)(big + (size_t)N * 128 * 8);               // [N,256]
    ushort_t* H2lo = (ushort_t*)(big + (size_t)N * 128 * 8 + (size_t)N * 256 * 2);
    float*    t3   = (float*)(big + (size_t)N * 128 * 8 + (size_t)N * 256 * 4);  // [N,128]
    float*    H3   = (float*)(big);                                        // [N,128] f32

    // ---- dtype detect + conversions ----
    detect_dtype_kernel<<<1, 256, 0, stream>>>((const unsigned int*)d_in[0], flag);
    convert_x_kernel<<<(N * 128 + 255) / 256, 256, 0, stream>>>(d_in[0], xf, N * 128, flag);
    {
        dim3 g((maxn + 255) / 256, 9);
        convert_many_kernel<<<g, 256, 0, stream>>>(wd, flag);
    }
    {
        WSplit ws;
        ws.src[0] = d_in[3]; ws.hi[0] = W1thi; ws.lo[0] = W1tlo; ws.K[0] = K1; ws.Nn[0] = N1;
        ws.src[1] = d_in[5]; ws.hi[1] = W2thi; ws.lo[1] = W2tlo; ws.K[1] = K2; ws.Nn[1] = N2;
        ws.src[2] = d_in[7]; ws.hi[2] = W3thi; ws.lo[2] = W3tlo; ws.K[2] = K3; ws.Nn[2] = N3;
        int maxw = K2 * N2;  // 131072
        dim3 g((maxw + 255) / 256, 3);
        wsplit_kernel<<<g, 256, 0, stream>>>(ws, flag);
    }

    // ---- CSR build ----
    init_deg_kernel<<<(N + 255) / 256, 256, 0, stream>>>(deg, N);
    count_deg_kernel<<<(E + 255) / 256, 256, 0, stream>>>(dstv, deg, E, N);
    scan_kernel<<<1, 1024, 0, stream>>>(deg, offsets, cursor, dis, N);
    fill_csr_kernel<<<(Etot + 255) / 256, 256, 0, stream>>>(srcv, dstv, cursor, csr_src,
                                                            E, N, Etot);

    // ---- pipeline ----
    // t0 = A x  -> split bf16
    agg_kernel<1><<<N, 128, 0, stream>>>(xf, nullptr, T0hi, T0lo, offsets, csr_src, dis,
                                         128, N, Etot, nullptr, 0);
    // H1 = lrelu(t0 W1 + b1) -> split bf16  [N,512]
    {
        dim3 g(N1 / 64, (N + 127) / 128);
        mfma_gemm_kernel<1><<<g, 256, 0, stream>>>(T0hi, T0lo, W1thi, W1tlo,
                                                   nullptr, H1hi, H1lo,
                                                   N, K1, N1, b1, 1);
    }
    // t2 = H1 W2 -> f32  [N,256]
    {
        dim3 g(N2 / 64, (N + 127) / 128);
        mfma_gemm_kernel<0><<<g, 256, 0, stream>>>(H1hi, H1lo, W2thi, W2tlo,
                                                   t2, nullptr, nullptr,
                                                   N, K2, N2, nullptr, 0);
    }
    // H2 = lrelu(A t2 + b2) -> split bf16  [N,256]
    agg_kernel<1><<<N, 256, 0, stream>>>(t2, nullptr, H2hi, H2lo, offsets, csr_src, dis,
                                         256, N, Etot, b2, 1);
    // t3 = H2 W3 -> f32  [N,128]
    {
        dim3 g(N3 / 64, (N + 127) / 128);
        mfma_gemm_kernel<0><<<g, 256, 0, stream>>>(H2hi, H2lo, W3thi, W3tlo,
                                                   t3, nullptr, nullptr,
                                                   N, K3, N3, nullptr, 0);
    }
    // H3 = lrelu(A t3 + b3) -> f32  [N,128]
    agg_kernel<0><<<N, 128, 0, stream>>>(t3, H3, nullptr, nullptr, offsets, csr_src, dis,
                                         128, N, Etot, b3, 1);
    // head
    head_kernel<<<(N + 255) / 256, 256, 0, stream>>>(H3, Wp, bp, Wf1, bf1v, Wf2, bf2v,
                                                     d_out, N, flag);
}

// Round 6
// 348.778 us; speedup vs baseline: 1.6775x; 1.2734x over previous
//
#include <hip/hip_runtime.h>
#include <hip/hip_bf16.h>

typedef __hip_bfloat16 bf16;
typedef unsigned short ushort_t;
typedef __attribute__((ext_vector_type(8))) short short8v;
typedef __attribute__((ext_vector_type(4))) float floatx4;

#define NEG_SLOPE 0.15f

__device__ __forceinline__ float us2f(unsigned short u) {
    unsigned int x = ((unsigned int)u) << 16;
    float f;
    __builtin_memcpy(&f, &x, 4);
    return f;
}
__device__ __forceinline__ unsigned short f2us(float v) {
    bf16 h = __float2bfloat16(v);
    unsigned short u;
    __builtin_memcpy(&u, &h, 2);
    return u;
}
__device__ __forceinline__ void split2(float v, unsigned short& hi, unsigned short& lo) {
    hi = f2us(v);
    lo = f2us(v - us2f(hi));
}

// ------------------------------------------------------------ dtype detection
// flag=1 if x is packed bf16, 0 if fp32. Low 16 bits of first 1024 words:
// genuine bf16 of ~N(0,1) has exponent in [100,140] (or zero) essentially
// always; fp32 mantissa bits land there ~16% of the time.
__global__ void detect_dtype_kernel(const unsigned int* __restrict__ xw,
                                    int* __restrict__ flag) {
    __shared__ int cnt;
    int tid = threadIdx.x;
    if (tid == 0) cnt = 0;
    __syncthreads();
    int inr = 0;
    for (int k = 0; k < 4; ++k) {
        unsigned int w = xw[tid + k * 256];
        unsigned int e = (w >> 7) & 0xFF;
        if ((w & 0xFFFF) == 0 || (e >= 100 && e <= 140)) inr++;
    }
    atomicAdd(&cnt, inr);
    __syncthreads();
    if (tid == 0) flag[0] = (cnt >= 700) ? 1 : 0;
}

// x (either dtype) -> bf16 bits
__global__ void convert_x_kernel(const void* __restrict__ in, ushort_t* __restrict__ out,
                                 int n, const int* __restrict__ flag) {
    int i = blockIdx.x * blockDim.x + threadIdx.x;
    if (i >= n) return;
    out[i] = (*flag) ? ((const unsigned short*)in)[i] : f2us(((const float*)in)[i]);
}

// small tensors -> fp32
struct WtDesc {
    const void* src[9];
    float* dst[9];
    int n[9];
};

__global__ void convert_many_kernel(WtDesc d, const int* __restrict__ flag) {
    int t = blockIdx.y;
    int i = blockIdx.x * blockDim.x + threadIdx.x;
    if (i >= d.n[t]) return;
    d.dst[t][i] = (*flag) ? us2f(((const unsigned short*)d.src[t])[i])
                          : ((const float*)d.src[t])[i];
}

// W[K x Nn] (either dtype) -> Wt[Nn x K] bf16 bits
struct WTd {
    const void* src[3];
    ushort_t* dst[3];
    int K[3], Nn[3];
};

__global__ void transpose_w_kernel(WTd d, const int* __restrict__ flag) {
    int t = blockIdx.y;
    int i = blockIdx.x * blockDim.x + threadIdx.x;
    int K = d.K[t], Nn = d.Nn[t];
    if (i >= K * Nn) return;
    int n = i / K, k = i - n * K;
    size_t si = (size_t)k * Nn + n;
    d.dst[t][i] = (*flag) ? ((const unsigned short*)d.src[t])[si]
                          : f2us(((const float*)d.src[t])[si]);
}

// ---------------------------------------------------------------- CSR build
__global__ void init_deg_kernel(int* __restrict__ deg, int N) {
    int i = blockIdx.x * blockDim.x + threadIdx.x;
    if (i < N) deg[i] = 1;  // self-loop
}

__global__ void count_deg_kernel(const int* __restrict__ dst, int* __restrict__ deg,
                                 int E, int N) {
    int i = blockIdx.x * blockDim.x + threadIdx.x;
    if (i < E) {
        int d = dst[i];
        d = d < 0 ? 0 : (d >= N ? N - 1 : d);
        atomicAdd(&deg[d], 1);
    }
}

__global__ void scan_kernel(const int* __restrict__ deg, int* __restrict__ offsets,
                            int* __restrict__ cursor, float* __restrict__ dis, int N) {
    __shared__ int sh[1024];
    int tid = threadIdx.x;
    int chunk = (N + 1023) >> 10;
    int s = tid * chunk;
    int e = s + chunk; if (e > N) e = N;
    int sum = 0;
    for (int i = s; i < e; ++i) sum += deg[i];
    sh[tid] = sum;
    __syncthreads();
    for (int off = 1; off < 1024; off <<= 1) {
        int v = (tid >= off) ? sh[tid - off] : 0;
        __syncthreads();
        sh[tid] += v;
        __syncthreads();
    }
    int pre = (tid > 0) ? sh[tid - 1] : 0;
    for (int i = s; i < e; ++i) {
        offsets[i] = pre;
        cursor[i] = pre;
        int d = deg[i];
        dis[i] = rsqrtf((float)(d < 1 ? 1 : d));
        pre += d;
    }
    if (tid == 0) offsets[N] = sh[1023];
}

// edges[pos] = {src, bits(dis[src])}
__global__ void fill_csr_kernel(const int* __restrict__ src, const int* __restrict__ dst,
                                const float* __restrict__ dis, int* __restrict__ cursor,
                                int2* __restrict__ edges, int E, int N, int Etot) {
    int i = blockIdx.x * blockDim.x + threadIdx.x;
    int s, d;
    if (i < E) { s = src[i]; d = dst[i]; }
    else if (i < Etot) { s = d = i - E; }
    else return;
    s = s < 0 ? 0 : (s >= N ? N - 1 : s);
    d = d < 0 ? 0 : (d >= N ? N - 1 : d);
    int pos = atomicAdd(&cursor[d], 1);
    if (pos >= 0 && pos < Etot) edges[pos] = make_int2(s, __float_as_int(dis[s]));
}

// ---------------------------------------------------------------- aggregation
// Wave-per-node, lane holds VEC features. F = VEC*64. Gathers bf16 rows.
// OUT_MODE: 0 = fp32, 1 = split bf16
template <int VEC> struct LdT;
template <> struct LdT<2> { typedef unsigned int T; };
template <> struct LdT<4> { typedef uint2 T; };

template <int VEC>
__device__ __forceinline__ void addv(typename LdT<VEC>::T u, float w, float* acc);
template <>
__device__ __forceinline__ void addv<2>(unsigned int u, float w, float* acc) {
    acc[0] += w * us2f((unsigned short)(u & 0xFFFF));
    acc[1] += w * us2f((unsigned short)(u >> 16));
}
template <>
__device__ __forceinline__ void addv<4>(uint2 u, float w, float* acc) {
    acc[0] += w * us2f((unsigned short)(u.x & 0xFFFF));
    acc[1] += w * us2f((unsigned short)(u.x >> 16));
    acc[2] += w * us2f((unsigned short)(u.y & 0xFFFF));
    acc[3] += w * us2f((unsigned short)(u.y >> 16));
}

template <int VEC, int OUT_MODE>
__global__ __launch_bounds__(256) void agg_kernel(
    const ushort_t* __restrict__ Hin, float* __restrict__ OutF,
    ushort_t* __restrict__ Ohi, ushort_t* __restrict__ Olo,
    const int* __restrict__ offsets, const int2* __restrict__ edges,
    const float* __restrict__ dis, int N, int Etot,
    const float* __restrict__ bias, int do_lrelu) {
    typedef typename LdT<VEC>::T LT;
    const int F = VEC * 64;
    int lane = threadIdx.x & 63;
    int node = blockIdx.x * 4 + (threadIdx.x >> 6);
    if (node >= N) return;
    int beg = offsets[node], end = offsets[node + 1];
    beg = beg < 0 ? 0 : (beg > Etot ? Etot : beg);
    end = end < beg ? beg : (end > Etot ? Etot : end);

    float acc[VEC];
#pragma unroll
    for (int v = 0; v < VEC; ++v) acc[v] = 0.f;

    int fo = lane * VEC;
    int e = beg;
    for (; e + 4 <= end; e += 4) {
        int2 r0 = edges[e + 0], r1 = edges[e + 1], r2 = edges[e + 2], r3 = edges[e + 3];
        int s0 = r0.x, s1 = r1.x, s2 = r2.x, s3 = r3.x;
        s0 = s0 < 0 ? 0 : (s0 >= N ? N - 1 : s0);
        s1 = s1 < 0 ? 0 : (s1 >= N ? N - 1 : s1);
        s2 = s2 < 0 ? 0 : (s2 >= N ? N - 1 : s2);
        s3 = s3 < 0 ? 0 : (s3 >= N ? N - 1 : s3);
        LT u0 = *(const LT*)(Hin + (size_t)s0 * F + fo);
        LT u1 = *(const LT*)(Hin + (size_t)s1 * F + fo);
        LT u2 = *(const LT*)(Hin + (size_t)s2 * F + fo);
        LT u3 = *(const LT*)(Hin + (size_t)s3 * F + fo);
        addv<VEC>(u0, __int_as_float(r0.y), acc);
        addv<VEC>(u1, __int_as_float(r1.y), acc);
        addv<VEC>(u2, __int_as_float(r2.y), acc);
        addv<VEC>(u3, __int_as_float(r3.y), acc);
    }
    for (; e < end; ++e) {
        int2 r = edges[e];
        int s = r.x;
        s = s < 0 ? 0 : (s >= N ? N - 1 : s);
        LT u = *(const LT*)(Hin + (size_t)s * F + fo);
        addv<VEC>(u, __int_as_float(r.y), acc);
    }

    float dn = dis[node];
    size_t base = (size_t)node * F + fo;
#pragma unroll
    for (int v = 0; v < VEC; ++v) {
        float a = acc[v] * dn;
        if (bias) a += bias[fo + v];
        if (do_lrelu) a = (a > 0.f) ? a : a * NEG_SLOPE;
        if (OUT_MODE == 0) {
            OutF[base + v] = a;
        } else {
            unsigned short hi, lo;
            split2(a, hi, lo);
            Ohi[base + v] = hi;
            Olo[base + v] = lo;
        }
    }
}

// ---------------------------------------------------------------- MFMA GEMM
// C[M x Nn] = (Ahi+Alo)[M x K] * B, Bt[Nn x K] bf16.
// Tile 128x64, 4 waves, wave = 64x32 (4x2 tiles of 16x16x32). 2 MFMA per tile.
// OUT_MODE: 1 = split bf16 (C0=hi, C1=lo), 2 = single bf16 (C0)
template <int OUT_MODE>
__global__ __launch_bounds__(256) void mfma_gemm_kernel(
    const ushort_t* __restrict__ Ahi, const ushort_t* __restrict__ Alo,
    const ushort_t* __restrict__ Bt,
    ushort_t* __restrict__ C0, ushort_t* __restrict__ C1,
    int M, int K, int Nn, const float* __restrict__ bias, int do_lrelu) {
    __shared__ ushort_t Ah[128 * 40];
    __shared__ ushort_t Al[128 * 40];
    __shared__ ushort_t Bh[64 * 40];

    int tid = threadIdx.x;
    int row0 = blockIdx.y * 128;
    int col0 = blockIdx.x * 64;
    int lane = tid & 63;
    int w = tid >> 6;
    int quad = lane >> 4;
    int col = lane & 15;
    int wr = (w >> 1) * 64;
    int wc = (w & 1) * 32;

    floatx4 acc[4][2];
#pragma unroll
    for (int i = 0; i < 4; ++i)
#pragma unroll
        for (int j = 0; j < 2; ++j) acc[i][j] = (floatx4){0.f, 0.f, 0.f, 0.f};

    int arow = tid >> 1;           // 0..127
    int aseg = (tid & 1) * 16;     // 0 or 16
    int bcol = tid >> 2;           // 0..63
    int bseg = (tid & 3) * 8;      // 0,8,16,24

    for (int k0 = 0; k0 < K; k0 += 32) {
        {
            uint4 h0 = {0, 0, 0, 0}, h1 = {0, 0, 0, 0};
            uint4 l0 = {0, 0, 0, 0}, l1 = {0, 0, 0, 0};
            if (row0 + arow < M) {
                size_t g = (size_t)(row0 + arow) * K + k0 + aseg;
                h0 = *(const uint4*)(Ahi + g);
                h1 = *(const uint4*)(Ahi + g + 8);
                l0 = *(const uint4*)(Alo + g);
                l1 = *(const uint4*)(Alo + g + 8);
            }
            int lb = arow * 40 + aseg;
            *(uint4*)&Ah[lb] = h0;
            *(uint4*)&Ah[lb + 8] = h1;
            *(uint4*)&Al[lb] = l0;
            *(uint4*)&Al[lb + 8] = l1;
        }
        {
            size_t g = (size_t)(col0 + bcol) * K + k0 + bseg;
            *(uint4*)&Bh[bcol * 40 + bseg] = *(const uint4*)(Bt + g);
        }
        __syncthreads();

        short8v af_h[4], af_l[4], bf_h[2];
#pragma unroll
        for (int rt = 0; rt < 4; ++rt) {
            int r = (wr + rt * 16 + col) * 40 + quad * 8;
            af_h[rt] = *(const short8v*)&Ah[r];
            af_l[rt] = *(const short8v*)&Al[r];
        }
#pragma unroll
        for (int ct = 0; ct < 2; ++ct) {
            int c = (wc + ct * 16 + col) * 40 + quad * 8;
            bf_h[ct] = *(const short8v*)&Bh[c];
        }
#pragma unroll
        for (int rt = 0; rt < 4; ++rt)
#pragma unroll
            for (int ct = 0; ct < 2; ++ct) {
                acc[rt][ct] = __builtin_amdgcn_mfma_f32_16x16x32_bf16(
                    af_h[rt], bf_h[ct], acc[rt][ct], 0, 0, 0);
                acc[rt][ct] = __builtin_amdgcn_mfma_f32_16x16x32_bf16(
                    af_l[rt], bf_h[ct], acc[rt][ct], 0, 0, 0);
            }
        __syncthreads();
    }

    // epilogue: C/D layout col=lane&15, row=quad*4+reg
#pragma unroll
    for (int rt = 0; rt < 4; ++rt) {
#pragma unroll
        for (int ct = 0; ct < 2; ++ct) {
            int gcol = col0 + wc + ct * 16 + col;
            float bv = bias ? bias[gcol] : 0.f;
#pragma unroll
            for (int r = 0; r < 4; ++r) {
                int grow = row0 + wr + rt * 16 + quad * 4 + r;
                if (grow >= M) continue;
                float v = acc[rt][ct][r] + bv;
                if (do_lrelu) v = (v > 0.f) ? v : v * NEG_SLOPE;
                size_t idx = (size_t)grow * Nn + gcol;
                if (OUT_MODE == 1) {
                    unsigned short hi, lo;
                    split2(v, hi, lo);
                    C0[idx] = hi;
                    C1[idx] = lo;
                } else {
                    C0[idx] = f2us(v);
                }
            }
        }
    }
}

// ---------------------------------------------------------------- fused head
__global__ void head_kernel(const float* __restrict__ H,
                            const float* __restrict__ Wp, const float* __restrict__ bp,
                            const float* __restrict__ Wf1, const float* __restrict__ bf1v,
                            const float* __restrict__ Wf2, const float* __restrict__ bf2v,
                            void* __restrict__ out, int N, const int* __restrict__ flag) {
    int n = blockIdx.x * blockDim.x + threadIdx.x;
    if (n >= N) return;
    const float* h = H + (size_t)n * 128;
    float h4[16];
#pragma unroll
    for (int j = 0; j < 16; ++j) h4[j] = bp[j];
    for (int k = 0; k < 128; ++k) {
        float hv = h[k];
#pragma unroll
        for (int j = 0; j < 16; ++j) h4[j] += hv * Wp[k * 16 + j];
    }
    float h5[32];
#pragma unroll
    for (int j = 0; j < 32; ++j) h5[j] = bf1v[j];
#pragma unroll
    for (int k = 0; k < 16; ++k) {
#pragma unroll
        for (int j = 0; j < 32; ++j) h5[j] += h4[k] * Wf1[k * 32 + j];
    }
#pragma unroll
    for (int j = 0; j < 32; ++j) h5[j] = (h5[j] > 0.f) ? h5[j] : h5[j] * NEG_SLOPE;
    float o[2];
#pragma unroll
    for (int j = 0; j < 2; ++j) {
        float a = bf2v[j];
#pragma unroll
        for (int k = 0; k < 32; ++k) a += h5[k] * Wf2[k * 2 + j];
        o[j] = a;
    }
    if (*flag) {
        ushort_t* ob = (ushort_t*)out;
        ob[(size_t)n * 2 + 0] = f2us(o[0]);
        ob[(size_t)n * 2 + 1] = f2us(o[1]);
    } else {
        float* of = (float*)out;
        of[(size_t)n * 2 + 0] = o[0];
        of[(size_t)n * 2 + 1] = o[1];
    }
}

// ---------------------------------------------------------------- launch
extern "C" void kernel_launch(void* const* d_in, const int* in_sizes, int n_in,
                              void* d_out, int out_size, void* d_ws, size_t ws_size,
                              hipStream_t stream) {
    const int* ei = (const int*)d_in[1];

    const int N = in_sizes[0] / 128;   // 20000
    const int E = in_sizes[1] / 2;     // 320000
    const int Etot = E + N;
    const int* srcv = ei;
    const int* dstv = ei + E;

    uintptr_t p = (uintptr_t)d_ws;
    auto alloc = [&](size_t bytes) -> void* {
        p = (p + 255) & ~(uintptr_t)255;
        void* r = (void*)p;
        p += bytes;
        return r;
    };
    int*      flag    = (int*)alloc(4);
    ushort_t* xb      = (ushort_t*)alloc((size_t)N * 128 * 2);
    int*      deg     = (int*)alloc((size_t)N * 4);
    int*      offsets = (int*)alloc((size_t)(N + 1) * 4);
    int*      cursor  = (int*)alloc((size_t)N * 4);
    float*    dis     = (float*)alloc((size_t)N * 4);
    int2*     edges   = (int2*)alloc((size_t)Etot * 8);

    const int K1 = 128, N1 = 512, K2 = 512, N2 = 256, K3 = 256, N3 = 128;
    ushort_t* W1t = (ushort_t*)alloc((size_t)K1 * N1 * 2);
    ushort_t* W2t = (ushort_t*)alloc((size_t)K2 * N2 * 2);
    ushort_t* W3t = (ushort_t*)alloc((size_t)K3 * N3 * 2);

    // small fp32 tensors: b1,b2,b3, Wp,bp, Wf1,bf1, Wf2,bf2
    WtDesc wd;
    const int wmap[9] = {4, 6, 8, 9, 10, 11, 12, 13, 14};
    int maxn = 0;
    for (int t = 0; t < 9; ++t) {
        int n = in_sizes[wmap[t]];
        wd.src[t] = d_in[wmap[t]];
        wd.n[t] = n;
        wd.dst[t] = (float*)alloc((size_t)n * 4);
        if (n > maxn) maxn = n;
    }
    const float *b1 = wd.dst[0], *b2 = wd.dst[1], *b3 = wd.dst[2];
    const float *Wp = wd.dst[3], *bp = wd.dst[4];
    const float *Wf1 = wd.dst[5], *bf1v = wd.dst[6];
    const float *Wf2 = wd.dst[7], *bf2v = wd.dst[8];

    // R1: 40.96 MB, R2: 10.24 MB — aliased by lifetime
    char* R1 = (char*)alloc((size_t)N * 512 * 2 * 2);
    char* R2 = (char*)alloc((size_t)N * 128 * 4);
    ushort_t* T0hi = (ushort_t*)R2;                              // [N,128]
    ushort_t* T0lo = (ushort_t*)(R2 + (size_t)N * 128 * 2);
    ushort_t* H1hi = (ushort_t*)R1;                              // [N,512]
    ushort_t* H1lo = (ushort_t*)(R1 + (size_t)N * 512 * 2);
    ushort_t* t2   = (ushort_t*)R2;                              // [N,256] bf16
    ushort_t* H2hi = (ushort_t*)R1;                              // [N,256]
    ushort_t* H2lo = (ushort_t*)(R1 + (size_t)N * 256 * 2);
    ushort_t* t3   = (ushort_t*)(R1 + (size_t)N * 512 * 2);      // [N,128] bf16
    float*    H3   = (float*)R2;                                 // [N,128] f32

    // ---- dtype detect + conversions ----
    detect_dtype_kernel<<<1, 256, 0, stream>>>((const unsigned int*)d_in[0], flag);
    convert_x_kernel<<<(N * 128 + 255) / 256, 256, 0, stream>>>(d_in[0], xb, N * 128, flag);
    {
        dim3 g((maxn + 255) / 256, 9);
        convert_many_kernel<<<g, 256, 0, stream>>>(wd, flag);
    }
    {
        WTd wt;
        wt.src[0] = d_in[3]; wt.dst[0] = W1t; wt.K[0] = K1; wt.Nn[0] = N1;
        wt.src[1] = d_in[5]; wt.dst[1] = W2t; wt.K[1] = K2; wt.Nn[1] = N2;
        wt.src[2] = d_in[7]; wt.dst[2] = W3t; wt.K[2] = K3; wt.Nn[2] = N3;
        dim3 g((K2 * N2 + 255) / 256, 3);
        transpose_w_kernel<<<g, 256, 0, stream>>>(wt, flag);
    }

    // ---- CSR build ----
    init_deg_kernel<<<(N + 255) / 256, 256, 0, stream>>>(deg, N);
    count_deg_kernel<<<(E + 255) / 256, 256, 0, stream>>>(dstv, deg, E, N);
    scan_kernel<<<1, 1024, 0, stream>>>(deg, offsets, cursor, dis, N);
    fill_csr_kernel<<<(Etot + 255) / 256, 256, 0, stream>>>(srcv, dstv, dis, cursor,
                                                            edges, E, N, Etot);

    int aggGrid = (N + 3) / 4;
    // t0 = A x  -> split bf16
    agg_kernel<2, 1><<<aggGrid, 256, 0, stream>>>(xb, nullptr, T0hi, T0lo,
                                                  offsets, edges, dis, N, Etot,
                                                  nullptr, 0);
    // H1 = lrelu(t0 W1 + b1) -> split [N,512]
    {
        dim3 g(N1 / 64, (N + 127) / 128);
        mfma_gemm_kernel<1><<<g, 256, 0, stream>>>(T0hi, T0lo, W1t, H1hi, H1lo,
                                                   N, K1, N1, b1, 1);
    }
    // t2 = H1 W2 -> bf16 [N,256]
    {
        dim3 g(N2 / 64, (N + 127) / 128);
        mfma_gemm_kernel<2><<<g, 256, 0, stream>>>(H1hi, H1lo, W2t, t2, nullptr,
                                                   N, K2, N2, nullptr, 0);
    }
    // H2 = lrelu(A t2 + b2) -> split [N,256]
    agg_kernel<4, 1><<<aggGrid, 256, 0, stream>>>(t2, nullptr, H2hi, H2lo,
                                                  offsets, edges, dis, N, Etot,
                                                  b2, 1);
    // t3 = H2 W3 -> bf16 [N,128]
    {
        dim3 g(N3 / 64, (N + 127) / 128);
        mfma_gemm_kernel<2><<<g, 256, 0, stream>>>(H2hi, H2lo, W3t, t3, nullptr,
                                                   N, K3, N3, nullptr, 0);
    }
    // H3 = lrelu(A t3 + b3) -> f32 [N,128]
    agg_kernel<2, 0><<<aggGrid, 256, 0, stream>>>(t3, H3, nullptr, nullptr,
                                                  offsets, edges, dis, N, Etot,
                                                  b3, 1);
    // head
    head_kernel<<<(N + 255) / 256, 256, 0, stream>>>(H3, Wp, bp, Wf1, bf1v, Wf2, bf2v,
                                                     d_out, N, flag);
}

// Round 7
// 281.883 us; speedup vs baseline: 2.0756x; 1.2373x over previous
//
#include <hip/hip_runtime.h>
#include <hip/hip_bf16.h>

typedef __hip_bfloat16 bf16;
typedef unsigned short ushort_t;
typedef __attribute__((ext_vector_type(8))) short short8v;
typedef __attribute__((ext_vector_type(4))) float floatx4;

#define NEG_SLOPE 0.15f

__device__ __forceinline__ float us2f(unsigned short u) {
    unsigned int x = ((unsigned int)u) << 16;
    float f;
    __builtin_memcpy(&f, &x, 4);
    return f;
}
__device__ __forceinline__ unsigned short f2us(float v) {
    bf16 h = __float2bfloat16(v);
    unsigned short u;
    __builtin_memcpy(&u, &h, 2);
    return u;
}

// ------------------------------------------------------------ dtype detection
// flag=1 if x is packed bf16, 0 if fp32 (low 16 bits of fp32 are mantissa noise).
__global__ void detect_dtype_kernel(const unsigned int* __restrict__ xw,
                                    int* __restrict__ flag) {
    __shared__ int cnt;
    int tid = threadIdx.x;
    if (tid == 0) cnt = 0;
    __syncthreads();
    int inr = 0;
    for (int k = 0; k < 4; ++k) {
        unsigned int w = xw[tid + k * 256];
        unsigned int e = (w >> 7) & 0xFF;
        if ((w & 0xFFFF) == 0 || (e >= 100 && e <= 140)) inr++;
    }
    atomicAdd(&cnt, inr);
    __syncthreads();
    if (tid == 0) flag[0] = (cnt >= 700) ? 1 : 0;
}

// x (either dtype) -> bf16 bits
__global__ void convert_x_kernel(const void* __restrict__ in, ushort_t* __restrict__ out,
                                 int n, const int* __restrict__ flag) {
    int i = blockIdx.x * blockDim.x + threadIdx.x;
    if (i >= n) return;
    out[i] = (*flag) ? ((const unsigned short*)in)[i] : f2us(((const float*)in)[i]);
}

// 12 small prep tasks: K==0 -> fp32 convert; else transpose W[K x Nn] -> bf16 Wt[Nn x K]
struct PrepDesc {
    const void* src[12];
    void* dst[12];
    int n[12];
    int K[12], Nn[12];
};

__global__ void prep_small_kernel(PrepDesc d, const int* __restrict__ flag) {
    int t = blockIdx.y;
    int i = blockIdx.x * blockDim.x + threadIdx.x;
    if (i >= d.n[t]) return;
    int f = *flag;
    if (d.K[t] == 0) {
        ((float*)d.dst[t])[i] = f ? us2f(((const unsigned short*)d.src[t])[i])
                                  : ((const float*)d.src[t])[i];
    } else {
        int K = d.K[t], Nn = d.Nn[t];
        int n = i / K, k = i - n * K;
        size_t si = (size_t)k * Nn + n;
        ((ushort_t*)d.dst[t])[i] = f ? ((const unsigned short*)d.src[t])[si]
                                     : f2us(((const float*)d.src[t])[si]);
    }
}

// ---------------------------------------------------------------- CSR build
__global__ void count_deg_kernel(const int* __restrict__ dst, int* __restrict__ deg,
                                 int E, int N) {
    int i = blockIdx.x * blockDim.x + threadIdx.x;
    if (i < E) {
        int d = dst[i];
        d = d < 0 ? 0 : (d >= N ? N - 1 : d);
        atomicAdd(&deg[d], 1);
    }
}

// multi-block scan: A) per-block inclusive scan of (deg+1), B) scan block sums,
// C) finalize offsets/cursor/dis.
__global__ void scanA_kernel(const int* __restrict__ deg, int* __restrict__ incl,
                             int* __restrict__ bsum, int N) {
    __shared__ int sh[1024];
    int tid = threadIdx.x;
    int i = blockIdx.x * 1024 + tid;
    int v = (i < N) ? (deg[i] + 1) : 0;
    sh[tid] = v;
    __syncthreads();
    for (int off = 1; off < 1024; off <<= 1) {
        int t = (tid >= off) ? sh[tid - off] : 0;
        __syncthreads();
        sh[tid] += t;
        __syncthreads();
    }
    if (i < N) incl[i] = sh[tid];
    if (tid == 1023) bsum[blockIdx.x] = sh[1023];
}

__global__ void scanB_kernel(const int* __restrict__ bsum, int* __restrict__ boff, int nb) {
    if (threadIdx.x == 0) {
        int acc = 0;
        for (int b = 0; b < nb; ++b) { boff[b] = acc; acc += bsum[b]; }
        boff[nb] = acc;
    }
}

__global__ void scanC_kernel(const int* __restrict__ deg, const int* __restrict__ incl,
                             const int* __restrict__ boff, int* __restrict__ offsets,
                             int* __restrict__ cursor, float* __restrict__ dis, int N) {
    int i = blockIdx.x * 1024 + threadIdx.x;
    if (i >= N) return;
    int base = boff[blockIdx.x];
    int d = deg[i] + 1;
    int inc = incl[i];
    int excl = base + inc - d;
    offsets[i] = excl;
    cursor[i] = excl;
    dis[i] = rsqrtf((float)d);
    if (i == N - 1) offsets[N] = base + inc;
}

// edges[pos] = {src, bits(dis[src])}
__global__ void fill_csr_kernel(const int* __restrict__ src, const int* __restrict__ dst,
                                const float* __restrict__ dis, int* __restrict__ cursor,
                                int2* __restrict__ edges, int E, int N, int Etot) {
    int i = blockIdx.x * blockDim.x + threadIdx.x;
    int s, d;
    if (i < E) { s = src[i]; d = dst[i]; }
    else if (i < Etot) { s = d = i - E; }
    else return;
    s = s < 0 ? 0 : (s >= N ? N - 1 : s);
    d = d < 0 ? 0 : (d >= N ? N - 1 : d);
    int pos = atomicAdd(&cursor[d], 1);
    if (pos >= 0 && pos < Etot) edges[pos] = make_int2(s, __float_as_int(dis[s]));
}

// ---------------------------------------------------------------- aggregation
// Wave-per-node, lane holds VEC features. F = VEC*64. Gathers bf16 rows.
// OUT_MODE: 0 = fp32, 2 = packed bf16
template <int VEC> struct LdT;
template <> struct LdT<2> { typedef unsigned int T; };
template <> struct LdT<4> { typedef uint2 T; };

template <int VEC>
__device__ __forceinline__ void addv(typename LdT<VEC>::T u, float w, float* acc);
template <>
__device__ __forceinline__ void addv<2>(unsigned int u, float w, float* acc) {
    acc[0] += w * us2f((unsigned short)(u & 0xFFFF));
    acc[1] += w * us2f((unsigned short)(u >> 16));
}
template <>
__device__ __forceinline__ void addv<4>(uint2 u, float w, float* acc) {
    acc[0] += w * us2f((unsigned short)(u.x & 0xFFFF));
    acc[1] += w * us2f((unsigned short)(u.x >> 16));
    acc[2] += w * us2f((unsigned short)(u.y & 0xFFFF));
    acc[3] += w * us2f((unsigned short)(u.y >> 16));
}

template <int VEC, int OUT_MODE>
__global__ __launch_bounds__(256) void agg_kernel(
    const ushort_t* __restrict__ Hin, float* __restrict__ OutF,
    ushort_t* __restrict__ OutB,
    const int* __restrict__ offsets, const int2* __restrict__ edges,
    const float* __restrict__ dis, int N, int Etot,
    const float* __restrict__ bias, int do_lrelu) {
    typedef typename LdT<VEC>::T LT;
    const int F = VEC * 64;
    int lane = threadIdx.x & 63;
    int node = blockIdx.x * 4 + (threadIdx.x >> 6);
    if (node >= N) return;
    int beg = offsets[node], end = offsets[node + 1];
    beg = beg < 0 ? 0 : (beg > Etot ? Etot : beg);
    end = end < beg ? beg : (end > Etot ? Etot : end);

    float acc[VEC];
#pragma unroll
    for (int v = 0; v < VEC; ++v) acc[v] = 0.f;

    int fo = lane * VEC;
    int e = beg;
    for (; e + 4 <= end; e += 4) {
        int2 r0 = edges[e + 0], r1 = edges[e + 1], r2 = edges[e + 2], r3 = edges[e + 3];
        int s0 = r0.x, s1 = r1.x, s2 = r2.x, s3 = r3.x;
        s0 = s0 < 0 ? 0 : (s0 >= N ? N - 1 : s0);
        s1 = s1 < 0 ? 0 : (s1 >= N ? N - 1 : s1);
        s2 = s2 < 0 ? 0 : (s2 >= N ? N - 1 : s2);
        s3 = s3 < 0 ? 0 : (s3 >= N ? N - 1 : s3);
        LT u0 = *(const LT*)(Hin + (size_t)s0 * F + fo);
        LT u1 = *(const LT*)(Hin + (size_t)s1 * F + fo);
        LT u2 = *(const LT*)(Hin + (size_t)s2 * F + fo);
        LT u3 = *(const LT*)(Hin + (size_t)s3 * F + fo);
        addv<VEC>(u0, __int_as_float(r0.y), acc);
        addv<VEC>(u1, __int_as_float(r1.y), acc);
        addv<VEC>(u2, __int_as_float(r2.y), acc);
        addv<VEC>(u3, __int_as_float(r3.y), acc);
    }
    for (; e < end; ++e) {
        int2 r = edges[e];
        int s = r.x;
        s = s < 0 ? 0 : (s >= N ? N - 1 : s);
        LT u = *(const LT*)(Hin + (size_t)s * F + fo);
        addv<VEC>(u, __int_as_float(r.y), acc);
    }

    float dn = dis[node];
    size_t base = (size_t)node * F + fo;
    float outv[VEC];
#pragma unroll
    for (int v = 0; v < VEC; ++v) {
        float a = acc[v] * dn;
        if (bias) a += bias[fo + v];
        if (do_lrelu) a = (a > 0.f) ? a : a * NEG_SLOPE;
        outv[v] = a;
    }
    if (OUT_MODE == 0) {
#pragma unroll
        for (int v = 0; v < VEC; ++v) OutF[base + v] = outv[v];
    } else {
        if (VEC == 2) {
            unsigned int w = ((unsigned int)f2us(outv[1]) << 16) | f2us(outv[0]);
            *(unsigned int*)(OutB + base) = w;
        } else {
            uint2 w;
            w.x = ((unsigned int)f2us(outv[1]) << 16) | f2us(outv[0]);
            w.y = ((unsigned int)f2us(outv[3]) << 16) | f2us(outv[2]);
            *(uint2*)(OutB + base) = w;
        }
    }
}

// ---------------------------------------------------------------- MFMA GEMM
// C[M x Nn] (bf16) = A[M x K](bf16) * B, Bt[Nn x K] bf16; fp32 accumulate.
// Tile 128x64, 4 waves (2x2), wave = 64x32 (4x2 tiles of 16x16x32), 1 MFMA/tile.
__global__ __launch_bounds__(256) void mfma_gemm_kernel(
    const ushort_t* __restrict__ A, const ushort_t* __restrict__ Bt,
    ushort_t* __restrict__ C,
    int M, int K, int Nn, const float* __restrict__ bias, int do_lrelu) {
    __shared__ ushort_t As[128 * 40];
    __shared__ ushort_t Bs[64 * 40];

    int tid = threadIdx.x;
    int row0 = blockIdx.y * 128;
    int col0 = blockIdx.x * 64;
    int lane = tid & 63;
    int w = tid >> 6;
    int quad = lane >> 4;
    int col = lane & 15;
    int wr = (w >> 1) * 64;
    int wc = (w & 1) * 32;

    floatx4 acc[4][2];
#pragma unroll
    for (int i = 0; i < 4; ++i)
#pragma unroll
        for (int j = 0; j < 2; ++j) acc[i][j] = (floatx4){0.f, 0.f, 0.f, 0.f};

    int arow = tid >> 1;           // 0..127
    int aseg = (tid & 1) * 16;     // 0 or 16
    int bcol = tid >> 2;           // 0..63
    int bseg = (tid & 3) * 8;      // 0,8,16,24

    for (int k0 = 0; k0 < K; k0 += 32) {
        {
            uint4 h0 = {0, 0, 0, 0}, h1 = {0, 0, 0, 0};
            if (row0 + arow < M) {
                size_t g = (size_t)(row0 + arow) * K + k0 + aseg;
                h0 = *(const uint4*)(A + g);
                h1 = *(const uint4*)(A + g + 8);
            }
            int lb = arow * 40 + aseg;
            *(uint4*)&As[lb] = h0;
            *(uint4*)&As[lb + 8] = h1;
        }
        {
            size_t g = (size_t)(col0 + bcol) * K + k0 + bseg;
            *(uint4*)&Bs[bcol * 40 + bseg] = *(const uint4*)(Bt + g);
        }
        __syncthreads();

        short8v af[4], bf[2];
#pragma unroll
        for (int rt = 0; rt < 4; ++rt)
            af[rt] = *(const short8v*)&As[(wr + rt * 16 + col) * 40 + quad * 8];
#pragma unroll
        for (int ct = 0; ct < 2; ++ct)
            bf[ct] = *(const short8v*)&Bs[(wc + ct * 16 + col) * 40 + quad * 8];
#pragma unroll
        for (int rt = 0; rt < 4; ++rt)
#pragma unroll
            for (int ct = 0; ct < 2; ++ct)
                acc[rt][ct] = __builtin_amdgcn_mfma_f32_16x16x32_bf16(
                    af[rt], bf[ct], acc[rt][ct], 0, 0, 0);
        __syncthreads();
    }

    // epilogue: C/D layout col=lane&15, row=quad*4+reg
#pragma unroll
    for (int rt = 0; rt < 4; ++rt) {
#pragma unroll
        for (int ct = 0; ct < 2; ++ct) {
            int gcol = col0 + wc + ct * 16 + col;
            float bv = bias ? bias[gcol] : 0.f;
#pragma unroll
            for (int r = 0; r < 4; ++r) {
                int grow = row0 + wr + rt * 16 + quad * 4 + r;
                if (grow >= M) continue;
                float v = acc[rt][ct][r] + bv;
                if (do_lrelu) v = (v > 0.f) ? v : v * NEG_SLOPE;
                C[(size_t)grow * Nn + gcol] = f2us(v);
            }
        }
    }
}

// ---------------------------------------------------------------- fused head
__global__ void head_kernel(const float* __restrict__ H,
                            const float* __restrict__ Wp, const float* __restrict__ bp,
                            const float* __restrict__ Wf1, const float* __restrict__ bf1v,
                            const float* __restrict__ Wf2, const float* __restrict__ bf2v,
                            void* __restrict__ out, int N, const int* __restrict__ flag) {
    int n = blockIdx.x * blockDim.x + threadIdx.x;
    if (n >= N) return;
    const float* h = H + (size_t)n * 128;
    float h4[16];
#pragma unroll
    for (int j = 0; j < 16; ++j) h4[j] = bp[j];
    for (int k = 0; k < 128; ++k) {
        float hv = h[k];
#pragma unroll
        for (int j = 0; j < 16; ++j) h4[j] += hv * Wp[k * 16 + j];
    }
    float h5[32];
#pragma unroll
    for (int j = 0; j < 32; ++j) h5[j] = bf1v[j];
#pragma unroll
    for (int k = 0; k < 16; ++k) {
#pragma unroll
        for (int j = 0; j < 32; ++j) h5[j] += h4[k] * Wf1[k * 32 + j];
    }
#pragma unroll
    for (int j = 0; j < 32; ++j) h5[j] = (h5[j] > 0.f) ? h5[j] : h5[j] * NEG_SLOPE;
    float o[2];
#pragma unroll
    for (int j = 0; j < 2; ++j) {
        float a = bf2v[j];
#pragma unroll
        for (int k = 0; k < 32; ++k) a += h5[k] * Wf2[k * 2 + j];
        o[j] = a;
    }
    if (*flag) {
        ushort_t* ob = (ushort_t*)out;
        ob[(size_t)n * 2 + 0] = f2us(o[0]);
        ob[(size_t)n * 2 + 1] = f2us(o[1]);
    } else {
        float* of = (float*)out;
        of[(size_t)n * 2 + 0] = o[0];
        of[(size_t)n * 2 + 1] = o[1];
    }
}

// ---------------------------------------------------------------- launch
extern "C" void kernel_launch(void* const* d_in, const int* in_sizes, int n_in,
                              void* d_out, int out_size, void* d_ws, size_t ws_size,
                              hipStream_t stream) {
    const int* ei = (const int*)d_in[1];

    const int N = in_sizes[0] / 128;   // 20000
    const int E = in_sizes[1] / 2;     // 320000
    const int Etot = E + N;
    const int nb = (N + 1023) / 1024;
    const int* srcv = ei;
    const int* dstv = ei + E;

    uintptr_t p = (uintptr_t)d_ws;
    auto alloc = [&](size_t bytes) -> void* {
        p = (p + 255) & ~(uintptr_t)255;
        void* r = (void*)p;
        p += bytes;
        return r;
    };
    int*      flag    = (int*)alloc(4);
    ushort_t* xb      = (ushort_t*)alloc((size_t)N * 128 * 2);
    int*      deg     = (int*)alloc((size_t)N * 4);
    int*      offsets = (int*)alloc((size_t)(N + 1) * 4);
    int*      cursor  = (int*)alloc((size_t)N * 4);
    float*    dis     = (float*)alloc((size_t)N * 4);
    int*      incl    = (int*)alloc((size_t)N * 4);
    int*      bsum    = (int*)alloc((size_t)(nb + 1) * 4);
    int*      boff    = (int*)alloc((size_t)(nb + 1) * 4);
    int2*     edges   = (int2*)alloc((size_t)Etot * 8);

    const int K1 = 128, N1 = 512, K2 = 512, N2 = 256, K3 = 256, N3 = 128;
    ushort_t* W1t = (ushort_t*)alloc((size_t)K1 * N1 * 2);
    ushort_t* W2t = (ushort_t*)alloc((size_t)K2 * N2 * 2);
    ushort_t* W3t = (ushort_t*)alloc((size_t)K3 * N3 * 2);

    // small fp32 tensors: b1,b2,b3, Wp,bp, Wf1,bf1, Wf2,bf2
    float* smalls[9];
    const int wmap[9] = {4, 6, 8, 9, 10, 11, 12, 13, 14};
    for (int t = 0; t < 9; ++t)
        smalls[t] = (float*)alloc((size_t)in_sizes[wmap[t]] * 4);
    const float *b1 = smalls[0], *b2 = smalls[1], *b3 = smalls[2];
    const float *Wp = smalls[3], *bp = smalls[4];
    const float *Wf1 = smalls[5], *bf1v = smalls[6];
    const float *Wf2 = smalls[7], *bf2v = smalls[8];

    // big buffers (aliased by lifetime): ~35.8 MB
    ushort_t* BufT0 = (ushort_t*)alloc((size_t)N * 128 * 2);   // t0, then t3
    char*     BufH1 = (char*)alloc((size_t)N * 512 * 2);       // H1, then H2 + H3
    ushort_t* BufT2 = (ushort_t*)alloc((size_t)N * 256 * 2);   // t2
    ushort_t* t0 = BufT0;
    ushort_t* t3 = BufT0;
    ushort_t* H1 = (ushort_t*)BufH1;
    ushort_t* H2 = (ushort_t*)BufH1;                            // [N,256] first half
    float*    H3 = (float*)(BufH1 + (size_t)N * 256 * 2);       // [N,128] f32 second half
    ushort_t* t2 = BufT2;

    // ---- dtype detect + conversions ----
    detect_dtype_kernel<<<1, 256, 0, stream>>>((const unsigned int*)d_in[0], flag);
    convert_x_kernel<<<(N * 128 + 255) / 256, 256, 0, stream>>>(d_in[0], xb, N * 128, flag);
    {
        PrepDesc pd;
        for (int t = 0; t < 9; ++t) {
            pd.src[t] = d_in[wmap[t]];
            pd.dst[t] = smalls[t];
            pd.n[t] = in_sizes[wmap[t]];
            pd.K[t] = 0; pd.Nn[t] = 0;
        }
        pd.src[9]  = d_in[3]; pd.dst[9]  = W1t; pd.n[9]  = K1 * N1; pd.K[9]  = K1; pd.Nn[9]  = N1;
        pd.src[10] = d_in[5]; pd.dst[10] = W2t; pd.n[10] = K2 * N2; pd.K[10] = K2; pd.Nn[10] = N2;
        pd.src[11] = d_in[7]; pd.dst[11] = W3t; pd.n[11] = K3 * N3; pd.K[11] = K3; pd.Nn[11] = N3;
        dim3 g((K2 * N2 + 255) / 256, 12);
        prep_small_kernel<<<g, 256, 0, stream>>>(pd, flag);
    }

    // ---- CSR build ----
    hipMemsetAsync(deg, 0, (size_t)N * 4, stream);
    count_deg_kernel<<<(E + 255) / 256, 256, 0, stream>>>(dstv, deg, E, N);
    scanA_kernel<<<nb, 1024, 0, stream>>>(deg, incl, bsum, N);
    scanB_kernel<<<1, 64, 0, stream>>>(bsum, boff, nb);
    scanC_kernel<<<nb, 1024, 0, stream>>>(deg, incl, boff, offsets, cursor, dis, N);
    fill_csr_kernel<<<(Etot + 255) / 256, 256, 0, stream>>>(srcv, dstv, dis, cursor,
                                                            edges, E, N, Etot);

    int aggGrid = (N + 3) / 4;
    // t0 = A x -> bf16 [N,128]
    agg_kernel<2, 2><<<aggGrid, 256, 0, stream>>>(xb, nullptr, t0, offsets, edges, dis,
                                                  N, Etot, nullptr, 0);
    // H1 = lrelu(t0 W1 + b1) -> bf16 [N,512]
    {
        dim3 g(N1 / 64, (N + 127) / 128);
        mfma_gemm_kernel<<<g, 256, 0, stream>>>(t0, W1t, H1, N, K1, N1, b1, 1);
    }
    // t2 = H1 W2 -> bf16 [N,256]
    {
        dim3 g(N2 / 64, (N + 127) / 128);
        mfma_gemm_kernel<<<g, 256, 0, stream>>>(H1, W2t, t2, N, K2, N2, nullptr, 0);
    }
    // H2 = lrelu(A t2 + b2) -> bf16 [N,256]
    agg_kernel<4, 2><<<aggGrid, 256, 0, stream>>>(t2, nullptr, H2, offsets, edges, dis,
                                                  N, Etot, b2, 1);
    // t3 = H2 W3 -> bf16 [N,128]
    {
        dim3 g(N3 / 64, (N + 127) / 128);
        mfma_gemm_kernel<<<g, 256, 0, stream>>>(H2, W3t, t3, N, K3, N3, nullptr, 0);
    }
    // H3 = lrelu(A t3 + b3) -> f32 [N,128]
    agg_kernel<2, 0><<<aggGrid, 256, 0, stream>>>(t3, H3, nullptr, offsets, edges, dis,
                                                  N, Etot, b3, 1);
    // head
    head_kernel<<<(N + 255) / 256, 256, 0, stream>>>(H3, Wp, bp, Wf1, bf1v, Wf2, bf2v,
                                                     d_out, N, flag);
}

// Round 8
// 274.815 us; speedup vs baseline: 2.1289x; 1.0257x over previous
//
#include <hip/hip_runtime.h>
#include <hip/hip_bf16.h>

typedef __hip_bfloat16 bf16;
typedef unsigned short ushort_t;
typedef __attribute__((ext_vector_type(8))) short short8v;
typedef __attribute__((ext_vector_type(4))) float floatx4;

#define NEG_SLOPE 0.15f

__device__ __forceinline__ float us2f(unsigned short u) {
    unsigned int x = ((unsigned int)u) << 16;
    float f;
    __builtin_memcpy(&f, &x, 4);
    return f;
}
__device__ __forceinline__ unsigned short f2us(float v) {
    bf16 h = __float2bfloat16(v);
    unsigned short u;
    __builtin_memcpy(&u, &h, 2);
    return u;
}

// ------------------------------------------------------------ dtype detection
// flag=1 if x is packed bf16, 0 if fp32 (low 16 bits of fp32 are mantissa noise).
__global__ void detect_dtype_kernel(const unsigned int* __restrict__ xw,
                                    int* __restrict__ flag) {
    __shared__ int cnt;
    int tid = threadIdx.x;
    if (tid == 0) cnt = 0;
    __syncthreads();
    int inr = 0;
    for (int k = 0; k < 4; ++k) {
        unsigned int w = xw[tid + k * 256];
        unsigned int e = (w >> 7) & 0xFF;
        if ((w & 0xFFFF) == 0 || (e >= 100 && e <= 140)) inr++;
    }
    atomicAdd(&cnt, inr);
    __syncthreads();
    if (tid == 0) flag[0] = (cnt >= 700) ? 1 : 0;
}

// x (either dtype) -> bf16 bits
__global__ void convert_x_kernel(const void* __restrict__ in, ushort_t* __restrict__ out,
                                 int n, const int* __restrict__ flag) {
    int i = blockIdx.x * blockDim.x + threadIdx.x;
    if (i >= n) return;
    out[i] = (*flag) ? ((const unsigned short*)in)[i] : f2us(((const float*)in)[i]);
}

// 12 small prep tasks: K==0 -> fp32 convert; else transpose W[K x Nn] -> bf16 Wt[Nn x K]
struct PrepDesc {
    const void* src[12];
    void* dst[12];
    int n[12];
    int K[12], Nn[12];
};

__global__ void prep_small_kernel(PrepDesc d, const int* __restrict__ flag) {
    int t = blockIdx.y;
    int i = blockIdx.x * blockDim.x + threadIdx.x;
    if (i >= d.n[t]) return;
    int f = *flag;
    if (d.K[t] == 0) {
        ((float*)d.dst[t])[i] = f ? us2f(((const unsigned short*)d.src[t])[i])
                                  : ((const float*)d.src[t])[i];
    } else {
        int K = d.K[t], Nn = d.Nn[t];
        int n = i / K, k = i - n * K;
        size_t si = (size_t)k * Nn + n;
        ((ushort_t*)d.dst[t])[i] = f ? ((const unsigned short*)d.src[t])[si]
                                     : f2us(((const float*)d.src[t])[si]);
    }
}

// ---------------------------------------------------------------- CSR build
__global__ void count_deg_kernel(const int* __restrict__ dst, int* __restrict__ deg,
                                 int E, int N) {
    int i = blockIdx.x * blockDim.x + threadIdx.x;
    if (i < E) {
        int d = dst[i];
        d = d < 0 ? 0 : (d >= N ? N - 1 : d);
        atomicAdd(&deg[d], 1);
    }
}

// A) per-block inclusive scan of (deg+1); C) finalize (each block sums bsum prefix).
__global__ void scanA_kernel(const int* __restrict__ deg, int* __restrict__ incl,
                             int* __restrict__ bsum, int N) {
    __shared__ int sh[1024];
    int tid = threadIdx.x;
    int i = blockIdx.x * 1024 + tid;
    int v = (i < N) ? (deg[i] + 1) : 0;
    sh[tid] = v;
    __syncthreads();
    for (int off = 1; off < 1024; off <<= 1) {
        int t = (tid >= off) ? sh[tid - off] : 0;
        __syncthreads();
        sh[tid] += t;
        __syncthreads();
    }
    if (i < N) incl[i] = sh[tid];
    if (tid == 1023) bsum[blockIdx.x] = sh[1023];
}

__global__ void scanC_kernel(const int* __restrict__ deg, const int* __restrict__ incl,
                             const int* __restrict__ bsum, int* __restrict__ offsets,
                             int* __restrict__ cursor, float* __restrict__ dis, int N) {
    __shared__ int base_s;
    if (threadIdx.x == 0) {
        int a = 0;
        for (int b = 0; b < (int)blockIdx.x; ++b) a += bsum[b];
        base_s = a;
    }
    __syncthreads();
    int i = blockIdx.x * 1024 + threadIdx.x;
    if (i >= N) return;
    int base = base_s;
    int d = deg[i] + 1;
    int inc = incl[i];
    int excl = base + inc - d;
    offsets[i] = excl;
    cursor[i] = excl;
    dis[i] = rsqrtf((float)d);
    if (i == N - 1) offsets[N] = base + inc;
}

// edges[pos] = {src, bits(dis[src])}
__global__ void fill_csr_kernel(const int* __restrict__ src, const int* __restrict__ dst,
                                const float* __restrict__ dis, int* __restrict__ cursor,
                                int2* __restrict__ edges, int E, int N, int Etot) {
    int i = blockIdx.x * blockDim.x + threadIdx.x;
    int s, d;
    if (i < E) { s = src[i]; d = dst[i]; }
    else if (i < Etot) { s = d = i - E; }
    else return;
    s = s < 0 ? 0 : (s >= N ? N - 1 : s);
    d = d < 0 ? 0 : (d >= N ? N - 1 : d);
    int pos = atomicAdd(&cursor[d], 1);
    if (pos >= 0 && pos < Etot) edges[pos] = make_int2(s, __float_as_int(dis[s]));
}

// ---------------------------------------------------------------- aggregation
// Wave-per-node, lane holds VEC features. F = VEC*64. Gathers bf16 rows, 8-deep ILP.
template <int VEC> struct LdT;
template <> struct LdT<2> { typedef unsigned int T; };
template <> struct LdT<4> { typedef uint2 T; };

template <int VEC>
__device__ __forceinline__ void addv(typename LdT<VEC>::T u, float w, float* acc);
template <>
__device__ __forceinline__ void addv<2>(unsigned int u, float w, float* acc) {
    acc[0] += w * us2f((unsigned short)(u & 0xFFFF));
    acc[1] += w * us2f((unsigned short)(u >> 16));
}
template <>
__device__ __forceinline__ void addv<4>(uint2 u, float w, float* acc) {
    acc[0] += w * us2f((unsigned short)(u.x & 0xFFFF));
    acc[1] += w * us2f((unsigned short)(u.x >> 16));
    acc[2] += w * us2f((unsigned short)(u.y & 0xFFFF));
    acc[3] += w * us2f((unsigned short)(u.y >> 16));
}

template <int VEC>
__global__ __launch_bounds__(256) void agg_kernel(
    const ushort_t* __restrict__ Hin, ushort_t* __restrict__ OutB,
    const int* __restrict__ offsets, const int2* __restrict__ edges,
    const float* __restrict__ dis, int N, int Etot,
    const float* __restrict__ bias, int do_lrelu) {
    typedef typename LdT<VEC>::T LT;
    const int F = VEC * 64;
    int lane = threadIdx.x & 63;
    int node = blockIdx.x * 4 + (threadIdx.x >> 6);
    if (node >= N) return;
    int beg = offsets[node], end = offsets[node + 1];
    beg = beg < 0 ? 0 : (beg > Etot ? Etot : beg);
    end = end < beg ? beg : (end > Etot ? Etot : end);

    float acc[VEC];
#pragma unroll
    for (int v = 0; v < VEC; ++v) acc[v] = 0.f;

    int fo = lane * VEC;
    int e = beg;
    for (; e + 8 <= end; e += 8) {
        int2 r[8];
#pragma unroll
        for (int j = 0; j < 8; ++j) r[j] = edges[e + j];
        LT u[8];
#pragma unroll
        for (int j = 0; j < 8; ++j) {
            int s = r[j].x;
            s = s < 0 ? 0 : (s >= N ? N - 1 : s);
            u[j] = *(const LT*)(Hin + (size_t)s * F + fo);
        }
#pragma unroll
        for (int j = 0; j < 8; ++j) addv<VEC>(u[j], __int_as_float(r[j].y), acc);
    }
    if (e + 4 <= end) {
        int2 r[4];
#pragma unroll
        for (int j = 0; j < 4; ++j) r[j] = edges[e + j];
        LT u[4];
#pragma unroll
        for (int j = 0; j < 4; ++j) {
            int s = r[j].x;
            s = s < 0 ? 0 : (s >= N ? N - 1 : s);
            u[j] = *(const LT*)(Hin + (size_t)s * F + fo);
        }
#pragma unroll
        for (int j = 0; j < 4; ++j) addv<VEC>(u[j], __int_as_float(r[j].y), acc);
        e += 4;
    }
    for (; e < end; ++e) {
        int2 r = edges[e];
        int s = r.x;
        s = s < 0 ? 0 : (s >= N ? N - 1 : s);
        LT u = *(const LT*)(Hin + (size_t)s * F + fo);
        addv<VEC>(u, __int_as_float(r.y), acc);
    }

    float dn = dis[node];
    size_t base = (size_t)node * F + fo;
    float outv[VEC];
#pragma unroll
    for (int v = 0; v < VEC; ++v) {
        float a = acc[v] * dn;
        if (bias) a += bias[fo + v];
        if (do_lrelu) a = (a > 0.f) ? a : a * NEG_SLOPE;
        outv[v] = a;
    }
    if (VEC == 2) {
        unsigned int w = ((unsigned int)f2us(outv[1]) << 16) | f2us(outv[0]);
        *(unsigned int*)(OutB + base) = w;
    } else {
        uint2 w;
        w.x = ((unsigned int)f2us(outv[1]) << 16) | f2us(outv[0]);
        w.y = ((unsigned int)f2us(outv[3]) << 16) | f2us(outv[2]);
        *(uint2*)(OutB + base) = w;
    }
}

// ---------------------------------------------------------------- MFMA GEMM
// C[M x Nn] (bf16) = A[M x K](bf16) * B, Bt[Nn x K] bf16; fp32 accumulate.
// Tile 128x64, 4 waves (2x2), wave = 64x32 (4x2 tiles of 16x16x32), 1 MFMA/tile.
__global__ __launch_bounds__(256) void mfma_gemm_kernel(
    const ushort_t* __restrict__ A, const ushort_t* __restrict__ Bt,
    ushort_t* __restrict__ C,
    int M, int K, int Nn, const float* __restrict__ bias, int do_lrelu) {
    __shared__ ushort_t As[128 * 40];
    __shared__ ushort_t Bs[64 * 40];

    int tid = threadIdx.x;
    int row0 = blockIdx.y * 128;
    int col0 = blockIdx.x * 64;
    int lane = tid & 63;
    int w = tid >> 6;
    int quad = lane >> 4;
    int col = lane & 15;
    int wr = (w >> 1) * 64;
    int wc = (w & 1) * 32;

    floatx4 acc[4][2];
#pragma unroll
    for (int i = 0; i < 4; ++i)
#pragma unroll
        for (int j = 0; j < 2; ++j) acc[i][j] = (floatx4){0.f, 0.f, 0.f, 0.f};

    int arow = tid >> 1;           // 0..127
    int aseg = (tid & 1) * 16;     // 0 or 16
    int bcol = tid >> 2;           // 0..63
    int bseg = (tid & 3) * 8;      // 0,8,16,24

    for (int k0 = 0; k0 < K; k0 += 32) {
        {
            uint4 h0 = {0, 0, 0, 0}, h1 = {0, 0, 0, 0};
            if (row0 + arow < M) {
                size_t g = (size_t)(row0 + arow) * K + k0 + aseg;
                h0 = *(const uint4*)(A + g);
                h1 = *(const uint4*)(A + g + 8);
            }
            int lb = arow * 40 + aseg;
            *(uint4*)&As[lb] = h0;
            *(uint4*)&As[lb + 8] = h1;
        }
        {
            size_t g = (size_t)(col0 + bcol) * K + k0 + bseg;
            *(uint4*)&Bs[bcol * 40 + bseg] = *(const uint4*)(Bt + g);
        }
        __syncthreads();

        short8v af[4], bf[2];
#pragma unroll
        for (int rt = 0; rt < 4; ++rt)
            af[rt] = *(const short8v*)&As[(wr + rt * 16 + col) * 40 + quad * 8];
#pragma unroll
        for (int ct = 0; ct < 2; ++ct)
            bf[ct] = *(const short8v*)&Bs[(wc + ct * 16 + col) * 40 + quad * 8];
#pragma unroll
        for (int rt = 0; rt < 4; ++rt)
#pragma unroll
            for (int ct = 0; ct < 2; ++ct)
                acc[rt][ct] = __builtin_amdgcn_mfma_f32_16x16x32_bf16(
                    af[rt], bf[ct], acc[rt][ct], 0, 0, 0);
        __syncthreads();
    }

    // epilogue: C/D layout col=lane&15, row=quad*4+reg
#pragma unroll
    for (int rt = 0; rt < 4; ++rt) {
#pragma unroll
        for (int ct = 0; ct < 2; ++ct) {
            int gcol = col0 + wc + ct * 16 + col;
            float bv = bias ? bias[gcol] : 0.f;
#pragma unroll
            for (int r = 0; r < 4; ++r) {
                int grow = row0 + wr + rt * 16 + quad * 4 + r;
                if (grow >= M) continue;
                float v = acc[rt][ct][r] + bv;
                if (do_lrelu) v = (v > 0.f) ? v : v * NEG_SLOPE;
                C[(size_t)grow * Nn + gcol] = f2us(v);
            }
        }
    }
}

// ---------------------------------------------------------------- fused head
__global__ void head_kernel(const ushort_t* __restrict__ H,
                            const float* __restrict__ Wp, const float* __restrict__ bp,
                            const float* __restrict__ Wf1, const float* __restrict__ bf1v,
                            const float* __restrict__ Wf2, const float* __restrict__ bf2v,
                            void* __restrict__ out, int N, const int* __restrict__ flag) {
    int n = blockIdx.x * blockDim.x + threadIdx.x;
    if (n >= N) return;
    const ushort_t* h = H + (size_t)n * 128;
    float h4[16];
#pragma unroll
    for (int j = 0; j < 16; ++j) h4[j] = bp[j];
    for (int k = 0; k < 128; ++k) {
        float hv = us2f(h[k]);
#pragma unroll
        for (int j = 0; j < 16; ++j) h4[j] += hv * Wp[k * 16 + j];
    }
    float h5[32];
#pragma unroll
    for (int j = 0; j < 32; ++j) h5[j] = bf1v[j];
#pragma unroll
    for (int k = 0; k < 16; ++k) {
#pragma unroll
        for (int j = 0; j < 32; ++j) h5[j] += h4[k] * Wf1[k * 32 + j];
    }
#pragma unroll
    for (int j = 0; j < 32; ++j) h5[j] = (h5[j] > 0.f) ? h5[j] : h5[j] * NEG_SLOPE;
    float o[2];
#pragma unroll
    for (int j = 0; j < 2; ++j) {
        float a = bf2v[j];
#pragma unroll
        for (int k = 0; k < 32; ++k) a += h5[k] * Wf2[k * 2 + j];
        o[j] = a;
    }
    if (*flag) {
        ushort_t* ob = (ushort_t*)out;
        ob[(size_t)n * 2 + 0] = f2us(o[0]);
        ob[(size_t)n * 2 + 1] = f2us(o[1]);
    } else {
        float* of = (float*)out;
        of[(size_t)n * 2 + 0] = o[0];
        of[(size_t)n * 2 + 1] = o[1];
    }
}

// ---------------------------------------------------------------- launch
extern "C" void kernel_launch(void* const* d_in, const int* in_sizes, int n_in,
                              void* d_out, int out_size, void* d_ws, size_t ws_size,
                              hipStream_t stream) {
    const int* ei = (const int*)d_in[1];

    const int N = in_sizes[0] / 128;   // 20000
    const int E = in_sizes[1] / 2;     // 320000
    const int Etot = E + N;
    const int nb = (N + 1023) / 1024;
    const int* srcv = ei;
    const int* dstv = ei + E;

    uintptr_t p = (uintptr_t)d_ws;
    auto alloc = [&](size_t bytes) -> void* {
        p = (p + 255) & ~(uintptr_t)255;
        void* r = (void*)p;
        p += bytes;
        return r;
    };
    int*      flag    = (int*)alloc(4);
    ushort_t* xb      = (ushort_t*)alloc((size_t)N * 128 * 2);
    int*      deg     = (int*)alloc((size_t)N * 4);
    int*      offsets = (int*)alloc((size_t)(N + 1) * 4);
    int*      cursor  = (int*)alloc((size_t)N * 4);
    float*    dis     = (float*)alloc((size_t)N * 4);
    int*      incl    = (int*)alloc((size_t)N * 4);
    int*      bsum    = (int*)alloc((size_t)(nb + 1) * 4);
    int2*     edges   = (int2*)alloc((size_t)Etot * 8);

    const int K1 = 128, N1 = 512, K2 = 512, N2 = 256, K3 = 256, N3 = 128;
    ushort_t* W1t = (ushort_t*)alloc((size_t)K1 * N1 * 2);
    ushort_t* W2t = (ushort_t*)alloc((size_t)K2 * N2 * 2);
    ushort_t* W3t = (ushort_t*)alloc((size_t)K3 * N3 * 2);

    // small fp32 tensors: b1,b2,b3, Wp,bp, Wf1,bf1, Wf2,bf2
    float* smalls[9];
    const int wmap[9] = {4, 6, 8, 9, 10, 11, 12, 13, 14};
    for (int t = 0; t < 9; ++t)
        smalls[t] = (float*)alloc((size_t)in_sizes[wmap[t]] * 4);
    const float *b1 = smalls[0], *b2 = smalls[1], *b3 = smalls[2];
    const float *Wp = smalls[3], *bp = smalls[4];
    const float *Wf1 = smalls[5], *bf1v = smalls[6];
    const float *Wf2 = smalls[7], *bf2v = smalls[8];

    // big buffers (aliased by lifetime)
    ushort_t* BufT0 = (ushort_t*)alloc((size_t)N * 128 * 2);   // t0, then t3
    char*     BufH1 = (char*)alloc((size_t)N * 512 * 2);       // H1, then H2 + H3
    ushort_t* BufT2 = (ushort_t*)alloc((size_t)N * 256 * 2);   // t2
    ushort_t* t0 = BufT0;
    ushort_t* t3 = BufT0;
    ushort_t* H1 = (ushort_t*)BufH1;
    ushort_t* H2 = (ushort_t*)BufH1;                            // [N,256] first half
    ushort_t* H3 = (ushort_t*)(BufH1 + (size_t)N * 256 * 2);    // [N,128] bf16
    ushort_t* t2 = BufT2;

    // ---- dtype detect + conversions ----
    detect_dtype_kernel<<<1, 256, 0, stream>>>((const unsigned int*)d_in[0], flag);
    convert_x_kernel<<<(N * 128 + 255) / 256, 256, 0, stream>>>(d_in[0], xb, N * 128, flag);
    {
        PrepDesc pd;
        for (int t = 0; t < 9; ++t) {
            pd.src[t] = d_in[wmap[t]];
            pd.dst[t] = smalls[t];
            pd.n[t] = in_sizes[wmap[t]];
            pd.K[t] = 0; pd.Nn[t] = 0;
        }
        pd.src[9]  = d_in[3]; pd.dst[9]  = W1t; pd.n[9]  = K1 * N1; pd.K[9]  = K1; pd.Nn[9]  = N1;
        pd.src[10] = d_in[5]; pd.dst[10] = W2t; pd.n[10] = K2 * N2; pd.K[10] = K2; pd.Nn[10] = N2;
        pd.src[11] = d_in[7]; pd.dst[11] = W3t; pd.n[11] = K3 * N3; pd.K[11] = K3; pd.Nn[11] = N3;
        dim3 g((K2 * N2 + 255) / 256, 12);
        prep_small_kernel<<<g, 256, 0, stream>>>(pd, flag);
    }

    // ---- CSR build ----
    hipMemsetAsync(deg, 0, (size_t)N * 4, stream);
    count_deg_kernel<<<(E + 255) / 256, 256, 0, stream>>>(dstv, deg, E, N);
    scanA_kernel<<<nb, 1024, 0, stream>>>(deg, incl, bsum, N);
    scanC_kernel<<<nb, 1024, 0, stream>>>(deg, incl, bsum, offsets, cursor, dis, N);
    fill_csr_kernel<<<(Etot + 255) / 256, 256, 0, stream>>>(srcv, dstv, dis, cursor,
                                                            edges, E, N, Etot);

    int aggGrid = (N + 3) / 4;
    // t0 = A x -> bf16 [N,128]
    agg_kernel<2><<<aggGrid, 256, 0, stream>>>(xb, t0, offsets, edges, dis,
                                               N, Etot, nullptr, 0);
    // H1 = lrelu(t0 W1 + b1) -> bf16 [N,512]
    {
        dim3 g(N1 / 64, (N + 127) / 128);
        mfma_gemm_kernel<<<g, 256, 0, stream>>>(t0, W1t, H1, N, K1, N1, b1, 1);
    }
    // t2 = H1 W2 -> bf16 [N,256]
    {
        dim3 g(N2 / 64, (N + 127) / 128);
        mfma_gemm_kernel<<<g, 256, 0, stream>>>(H1, W2t, t2, N, K2, N2, nullptr, 0);
    }
    // H2 = lrelu(A t2 + b2) -> bf16 [N,256]
    agg_kernel<4><<<aggGrid, 256, 0, stream>>>(t2, H2, offsets, edges, dis,
                                               N, Etot, b2, 1);
    // t3 = H2 W3 -> bf16 [N,128]
    {
        dim3 g(N3 / 64, (N + 127) / 128);
        mfma_gemm_kernel<<<g, 256, 0, stream>>>(H2, W3t, t3, N, K3, N3, nullptr, 0);
    }
    // H3 = lrelu(A t3 + b3) -> bf16 [N,128]
    agg_kernel<2><<<aggGrid, 256, 0, stream>>>(t3, H3, offsets, edges, dis,
                                               N, Etot, b3, 1);
    // head
    head_kernel<<<(N + 255) / 256, 256, 0, stream>>>(H3, Wp, bp, Wf1, bf1v, Wf2, bf2v,
                                                     d_out, N, flag);
}